// Round 12
// baseline (912.347 us; speedup 1.0000x reference)
//
#include <hip/hip_runtime.h>
#include <hip/hip_fp16.h>
#include <math.h>

// Problem constants: F_IN=64, K=16, C=20, L=4, H1=20, H2=2
// N=100k nodes, E=1.6M undirected edges, M=2E=3.2M directed entries.
//
// R10/R11 lesson: the analytic filter eval costs 252 VGPR when nested inside
// a scatter loop, 32 VGPR when phase-isolated (R9 filter). R12: passC phases:
// A) LDS sort + payload staging (chunk-grouped reads, in-phase across blocks)
// B) phase-isolated w2 eval from LDS attr -> coalesced pw2 (aliases tmp)
// C) coalesced fin/pw1 write-out. Gathers read sequential streams; x_h random
// reads are class-localized (sort key own7*16 + nbr>>13). WS = 108.9 MB.

#define SHIFT   7
#define NB_MAX  1024
#define CHUNKB  6144
#define BCAP    4608

// ---------------- K1: filter net + prep (block-range split) ---------------------
// fp16 mode (w1f==null): layer-1 only -> wedge1h. Fallback: fp32 both layers.
__global__ __launch_bounds__(256) void filter_prep_kernel(
    const float* __restrict__ attr, const float* __restrict__ cutoffs,
    const float* __restrict__ cw1, const float* __restrict__ cb1,
    const float* __restrict__ f1w1, const float* __restrict__ f1b1,
    const float* __restrict__ f2w1, const float* __restrict__ f2b1,
    const float* __restrict__ cw2, const float* __restrict__ cb2,
    const float* __restrict__ f1w2, const float* __restrict__ f1b2,
    const float* __restrict__ f2w2, const float* __restrict__ f2b2,
    uint2* __restrict__ wedge1h, float4* __restrict__ w1f, float4* __restrict__ w2f,
    int* __restrict__ bcur, int NB, int E,
    const float* __restrict__ x, const float* __restrict__ root1,
    const float* __restrict__ bias1, float* __restrict__ h1,
    __half* __restrict__ x_h, int N, int FB)
{
    int tid = threadIdx.x;
    if ((int)blockIdx.x >= FB) {
        __shared__ float r1s[64 * 21];
        __shared__ float sb[20];
        for (int i = tid; i < 1280; i += 256) {
            int f = i / 20, h = i % 20;
            r1s[f*21 + h] = root1[i];
        }
        if (tid < 20) sb[tid] = bias1[tid];
        __syncthreads();
        int t = ((int)blockIdx.x - FB) * 256 + tid;
        int n = t >> 3, q = t & 7;
        if (n >= N) return;
        const float4* xr = (const float4*)(x + (size_t)n*64 + q*8);
        float4 va = xr[0], vb = xr[1];
        float xf[8] = {va.x, va.y, va.z, va.w, vb.x, vb.y, vb.z, vb.w};
        __half hh[8];
        #pragma unroll
        for (int j = 0; j < 8; ++j) hh[j] = __float2half(xf[j]);
        *(uint4*)(x_h + (size_t)n*64 + q*8) = *(const uint4*)hh;
        float p[20];
        #pragma unroll
        for (int h = 0; h < 20; ++h) p[h] = 0.f;
        #pragma unroll
        for (int j = 0; j < 8; ++j) {
            float xv = xf[j];
            int base = (q*8 + j) * 21;
            #pragma unroll
            for (int h = 0; h < 20; ++h) p[h] += xv * r1s[base + h];
        }
        #pragma unroll
        for (int m = 1; m < 8; m <<= 1) {
            #pragma unroll
            for (int h = 0; h < 20; ++h) p[h] += __shfl_xor(p[h], m, 64);
        }
        if (q < 5) {
            float4 o;
            o.x = p[q*4+0] + sb[q*4+0];
            o.y = p[q*4+1] + sb[q*4+1];
            o.z = p[q*4+2] + sb[q*4+2];
            o.w = p[q*4+3] + sb[q*4+3];
            *(float4*)(h1 + (size_t)n*20 + q*4) = o;
        }
        return;
    }
    // ---------------- filter body ----------------
    __shared__ float s_cut[16];
    __shared__ float s_w[2][344];
    __shared__ float tab[2 * 20 * 64];
    int gb = blockIdx.x * 256 + tid;
    if (gb < NB) bcur[gb] = gb * BCAP;
    if (tid < 16) s_cut[tid] = cutoffs[tid];
    for (int i = tid; i < 344; i += 256) {
        float v1, v2;
        if (i < 120)      { v1 = cw1[i];       v2 = cw2[i]; }
        else if (i < 140) { v1 = cb1[i-120];   v2 = cb2[i-120]; }
        else if (i < 300) { v1 = f1w1[i-140];  v2 = f1w2[i-140]; }
        else if (i < 308) { v1 = f1b1[i-300];  v2 = f1b2[i-300]; }
        else if (i < 340) { v1 = f2w1[i-308];  v2 = f2w2[i-308]; }
        else              { v1 = f2b1[i-340];  v2 = f2b2[i-340]; }
        s_w[0][i] = v1; s_w[1][i] = v2;
    }
    __syncthreads();
    if (tid < 40) {
        int l = tid / 20, ch = tid % 20;
        const float* W = s_w[l];
        float w00 = W[ch*6+0], w01 = W[ch*6+1], w02 = W[ch*6+2];
        float w10 = W[ch*6+3], w11 = W[ch*6+4], w12 = W[ch*6+5];
        float b = W[120 + ch];
        float* tb = &tab[(l*20 + ch) * 64];
        tb[0]  = w01*s_cut[0]  + w02*s_cut[1];
        for (int k = 1; k <= 14; ++k)
            tb[k] = w00*s_cut[k-1] + w01*s_cut[k] + w02*s_cut[k+1];
        tb[15] = w00*s_cut[14] + w01*s_cut[15];
        float pm = tb[1]; tb[16+1] = pm;
        for (int j = 2; j <= 14; ++j) { pm = fminf(pm, tb[j]); tb[16+j] = pm; }
        float qm = tb[14]; tb[32+14] = qm;
        for (int j = 13; j >= 1; --j) { qm = fminf(qm, tb[j]); tb[32+j] = qm; }
        tb[48] = w00 + w01 + w02;
        tb[49] = w01 + w02;
        tb[50] = w00 + w01;
        tb[51] = w10 + w11 + w12;
        tb[52] = w10 + w11;
        tb[53] = w10;
        tb[54] = w11;
        tb[55] = w12;
        tb[56] = b;
        tb[57] = tb[0];
        tb[58] = tb[15];
        tb[59] = 0.f;
    }
    __syncthreads();
    int e = gb;
    if (e >= E) return;

    float a = attr[e];
    int idx = 0;
    #pragma unroll
    for (int k = 0; k < 16; ++k) idx += (a > s_cut[k]) ? 1 : 0;

    int nLayers = (w1f != nullptr) ? 2 : 1;
    for (int layer = 0; layer < nLayers; ++layer) {
        const float* W = s_w[layer];
        float h[20];
        #pragma unroll
        for (int c = 0; c < 20; ++c) {
            const float* tb = &tab[(layer*20 + c) * 64];
            const float4* tb4 = (const float4*)tb;
            float4 A  = tb4[12];
            float4 B  = tb4[13];
            float4 Cv = tb4[14];
            float b = Cv.x;
            float base = fmaf(A.x, a, b);
            float y0 = fmaf(A.y, a, b) - Cv.y;
            y0 += (idx >= 1 ? B.z : 0.f) + (idx >= 2 ? B.w : 0.f);
            float m = y0;
            float y15 = fmaf(A.z, a, b) - Cv.z;
            y15 += (idx >= 15 ? B.y : 0.f) + (idx >= 16 ? B.z : 0.f);
            m = fmaxf(m, y15);
            { int j = idx - 2; j = j > 14 ? 14 : j;
              float v = base + A.w - tb[16 + j];
              m = (idx >= 3) ? fmaxf(m, v) : m; }
            { float v = base + B.x - tb[(idx >= 2 && idx <= 15) ? (idx-1) : 1];
              m = (idx >= 2 && idx <= 15) ? fmaxf(m, v) : m; }
            { float v = base + B.y - tb[(idx >= 1 && idx <= 14) ? idx : 1];
              m = (idx >= 1 && idx <= 14) ? fmaxf(m, v) : m; }
            { int j = idx + 1; j = j < 1 ? 1 : j;
              float v = base - tb[32 + (j > 14 ? 14 : j)];
              m = (idx <= 13) ? fmaxf(m, v) : m; }
            h[c] = fmaxf(m, 0.f);
        }
        float g[8];
        {
            const float4* bj4 = (const float4*)&W[300];
            float4 bj0 = bj4[0], bj1 = bj4[1];
            float bj[8] = {bj0.x,bj0.y,bj0.z,bj0.w,bj1.x,bj1.y,bj1.z,bj1.w};
            #pragma unroll
            for (int j = 0; j < 8; ++j) {
                const float4* wj = (const float4*)&W[140 + j*20];
                float4 q0=wj[0], q1=wj[1], q2=wj[2], q3=wj[3], q4=wj[4];
                float t = bj[j];
                t += q0.x*h[0]  + q0.y*h[1]  + q0.z*h[2]  + q0.w*h[3];
                t += q1.x*h[4]  + q1.y*h[5]  + q1.z*h[6]  + q1.w*h[7];
                t += q2.x*h[8]  + q2.y*h[9]  + q2.z*h[10] + q2.w*h[11];
                t += q3.x*h[12] + q3.y*h[13] + q3.z*h[14] + q3.w*h[15];
                t += q4.x*h[16] + q4.y*h[17] + q4.z*h[18] + q4.w*h[19];
                g[j] = fmaxf(t, 0.f);
            }
        }
        float wv[4];
        {
            const float4* bl4 = (const float4*)&W[340];
            float4 bl = bl4[0];
            float blv[4] = {bl.x, bl.y, bl.z, bl.w};
            #pragma unroll
            for (int l = 0; l < 4; ++l) {
                const float4* wl = (const float4*)&W[308 + l*8];
                float4 r0 = wl[0], r1 = wl[1];
                float t = blv[l];
                t += r0.x*g[0] + r0.y*g[1] + r0.z*g[2] + r0.w*g[3];
                t += r1.x*g[4] + r1.y*g[5] + r1.z*g[6] + r1.w*g[7];
                wv[l] = fmaxf(t, 0.f);
            }
        }
        if (w1f != nullptr) {
            float4 wo = make_float4(wv[0], wv[1], wv[2], wv[3]);
            if (layer == 0) w1f[e] = wo; else w2f[e] = wo;
        } else {
            __half2 p01 = __floats2half2_rn(wv[0], wv[1]);
            __half2 p23 = __floats2half2_rn(wv[2], wv[3]);
            uint2 pk;
            pk.x = *(unsigned*)&p01;
            pk.y = *(unsigned*)&p23;
            wedge1h[e] = pk;
        }
    }
}

// ---------------- K2: scatter directed entries into capacity buckets ------------
// uint2 entry: x = nbr node, y = we | own7<<22  (ei read sequentially)
__global__ __launch_bounds__(256) void passB_kernel(
    const int* __restrict__ ei, int* __restrict__ bcur, uint2* __restrict__ tmp,
    int E, int M, int NB)
{
    __shared__ int hist[NB_MAX];
    __shared__ int lbase[NB_MAX];
    __shared__ int gpos[NB_MAX];
    __shared__ int aux[256];
    __shared__ uint2 stage[CHUNKB];
    int tid = threadIdx.x;
    int start = blockIdx.x * CHUNKB;
    if (start >= M) return;
    int cnt = M - start; if (cnt > CHUNKB) cnt = CHUNKB;
    for (int i = tid; i < NB_MAX; i += 256) hist[i] = 0;
    __syncthreads();
    for (int i = tid; i < cnt; i += 256) {
        int de = start + i;
        int own = ei[de < E ? de + E : de - E];
        atomicAdd(&hist[own >> SHIFT], 1);
    }
    __syncthreads();
    {
        int t4 = tid * 4;
        int a0 = hist[t4], a1 = hist[t4+1], a2 = hist[t4+2], a3 = hist[t4+3];
        aux[tid] = a0 + a1 + a2 + a3;
        __syncthreads();
        for (int off = 1; off < 256; off <<= 1) {
            int v = (tid >= off) ? aux[tid - off] : 0;
            __syncthreads();
            aux[tid] += v;
            __syncthreads();
        }
        int te = (tid == 0) ? 0 : aux[tid - 1];
        lbase[t4]   = te;
        lbase[t4+1] = te + a0;
        lbase[t4+2] = te + a0 + a1;
        lbase[t4+3] = te + a0 + a1 + a2;
    }
    __syncthreads();
    for (int b = tid; b < NB; b += 256) {
        int cb = hist[b];
        gpos[b] = cb ? atomicAdd(&bcur[b], cb) : 0;
    }
    __syncthreads();
    for (int i = tid; i < NB_MAX; i += 256) hist[i] = 0;
    __syncthreads();
    for (int i = tid; i < cnt; i += 256) {
        int de = start + i;
        int j = de < E ? de : de - E;
        int own = ei[de < E ? de + E : de - E];
        unsigned nbr = (unsigned)ei[de];
        int b = own >> SHIFT;
        int p = atomicAdd(&hist[b], 1);
        stage[lbase[b] + p] = make_uint2(nbr, (unsigned)j | ((unsigned)(own & 127) << 22));
    }
    __syncthreads();
    int wave = tid >> 6, lane = tid & 63;
    for (int b = wave; b < NB; b += 4) {
        int n_b = hist[b];
        if (!n_b) continue;
        int lo = lbase[b], g = gpos[b];
        int lim = (b + 1) * BCAP;
        for (int k = lane; k < n_b; k += 64) {
            if (g + k < lim) tmp[(size_t)g + k] = stage[lo + k];
        }
    }
}

// ---------------- K3: class-sort + stage payloads in LDS + coalesced out --------
// Phase A: sort into LDS (ord_nbr/ord_w1/ord_at), payload reads chunk-grouped.
// Phase B: phase-isolated w2 eval from ord_at -> pw2[lo+i] (aliases tmp).
// Phase C: coalesced fin/pw1 write-out.
__global__ __launch_bounds__(256) void passC_kernel(
    uint2* __restrict__ tmp /* in: entries, out: pw2 */, const int* __restrict__ bcur,
    const uint2* __restrict__ wedge1h, const float* __restrict__ attr,
    const float* __restrict__ cutoffs,
    const float* __restrict__ cw2, const float* __restrict__ cb2,
    const float* __restrict__ f1w2, const float* __restrict__ f1b2,
    const float* __restrict__ f2w2, const float* __restrict__ f2b2,
    unsigned* __restrict__ fin, uint2* __restrict__ pw1,
    int* __restrict__ off, int* __restrict__ deg, int E, int N)
{
    __shared__ uint2 ent[BCAP];
    __shared__ unsigned ord_nbr[BCAP];
    __shared__ uint2 ord_w1[BCAP];
    __shared__ float ord_at[BCAP];
    __shared__ int h2[2048];
    __shared__ int e2p[2048];
    __shared__ int aux[256];
    __shared__ float s_cut[16];
    __shared__ float Wl[344];
    __shared__ float tab[20 * 64];
    int tid = threadIdx.x;
    int b = blockIdx.x;
    int lo = b * BCAP;
    int cnt = bcur[b] - lo;
    if (cnt > BCAP) cnt = BCAP;
    if (tid < 16) s_cut[tid] = cutoffs[tid];
    for (int i = tid; i < 344; i += 256) {
        float v;
        if (i < 120)      v = cw2[i];
        else if (i < 140) v = cb2[i-120];
        else if (i < 300) v = f1w2[i-140];
        else if (i < 308) v = f1b2[i-300];
        else if (i < 340) v = f2w2[i-308];
        else              v = f2b2[i-340];
        Wl[i] = v;
    }
    for (int i = tid; i < cnt; i += 256) ent[i] = tmp[(size_t)lo + i];
    for (int i = tid; i < 2048; i += 256) h2[i] = 0;
    __syncthreads();
    if (tid < 20) {
        int ch = tid;
        float w00 = Wl[ch*6+0], w01 = Wl[ch*6+1], w02 = Wl[ch*6+2];
        float w10 = Wl[ch*6+3], w11 = Wl[ch*6+4], w12 = Wl[ch*6+5];
        float bb = Wl[120 + ch];
        float* tb = &tab[ch * 64];
        tb[0]  = w01*s_cut[0]  + w02*s_cut[1];
        for (int k = 1; k <= 14; ++k)
            tb[k] = w00*s_cut[k-1] + w01*s_cut[k] + w02*s_cut[k+1];
        tb[15] = w00*s_cut[14] + w01*s_cut[15];
        float pm = tb[1]; tb[16+1] = pm;
        for (int j = 2; j <= 14; ++j) { pm = fminf(pm, tb[j]); tb[16+j] = pm; }
        float qm = tb[14]; tb[32+14] = qm;
        for (int j = 13; j >= 1; --j) { qm = fminf(qm, tb[j]); tb[32+j] = qm; }
        tb[48] = w00 + w01 + w02;
        tb[49] = w01 + w02;
        tb[50] = w00 + w01;
        tb[51] = w10 + w11 + w12;
        tb[52] = w10 + w11;
        tb[53] = w10;
        tb[54] = w11;
        tb[55] = w12;
        tb[56] = bb;
        tb[57] = tb[0];
        tb[58] = tb[15];
        tb[59] = 0.f;
    }
    for (int i = tid; i < cnt; i += 256) {
        uint2 en = ent[i];
        atomicAdd(&h2[(en.y >> 22) * 16 + ((en.x >> 13) & 15)], 1);
    }
    __syncthreads();
    {   // exclusive scan h2 -> e2p
        int base8 = tid * 8;
        int v[8]; int s = 0;
        #pragma unroll
        for (int j = 0; j < 8; ++j) { v[j] = h2[base8 + j]; s += v[j]; }
        aux[tid] = s;
        __syncthreads();
        for (int o = 1; o < 256; o <<= 1) {
            int t = (tid >= o) ? aux[tid - o] : 0;
            __syncthreads();
            aux[tid] += t;
            __syncthreads();
        }
        int excl = (tid == 0) ? 0 : aux[tid - 1];
        int run = 0;
        #pragma unroll
        for (int j = 0; j < 8; ++j) { e2p[base8 + j] = excl + run; run += v[j]; }
    }
    __syncthreads();
    if (tid < 128) {
        int base = e2p[tid * 16];
        int next = (tid < 127) ? e2p[(tid + 1) * 16] : cnt;
        int node = (b << SHIFT) + tid;
        if (node < N) { off[node] = lo + base; deg[node] = next - base; }
    }
    for (int i = tid; i < 2048; i += 256) h2[i] = 0;  // reuse as cursor
    __syncthreads();
    // Phase A: scatter into LDS; payload reads in chunk-grouped (in-phase) order
    for (int i = tid; i < cnt; i += 256) {
        uint2 en = ent[i];
        unsigned nbr = en.x;
        unsigned we = en.y & 0x3FFFFFu;
        int key = (en.y >> 22) * 16 + ((nbr >> 13) & 15);
        int p = atomicAdd(&h2[key], 1);
        int pos = e2p[key] + p;
        ord_nbr[pos] = nbr;
        ord_w1[pos] = wedge1h[we];
        ord_at[pos] = attr[we];
    }
    __syncthreads();
    // Phase C: coalesced write-out of fin + pw1
    for (int i = tid; i < cnt; i += 256) {
        fin[(size_t)lo + i] = ord_nbr[i];
        pw1[(size_t)lo + i] = ord_w1[i];
    }
    // Phase B: phase-isolated analytic layer-2 eval -> pw2 (coalesced, aliases tmp)
    for (int i = tid; i < cnt; i += 256) {
        float a = ord_at[i];
        int idx = 0;
        #pragma unroll
        for (int k = 0; k < 16; ++k) idx += (a > s_cut[k]) ? 1 : 0;
        float h[20];
        #pragma unroll
        for (int ch = 0; ch < 20; ++ch) {
            const float* tb = &tab[ch * 64];
            const float4* tb4 = (const float4*)tb;
            float4 A  = tb4[12];
            float4 B  = tb4[13];
            float4 Cv = tb4[14];
            float bb = Cv.x;
            float base = fmaf(A.x, a, bb);
            float y0 = fmaf(A.y, a, bb) - Cv.y;
            y0 += (idx >= 1 ? B.z : 0.f) + (idx >= 2 ? B.w : 0.f);
            float m = y0;
            float y15 = fmaf(A.z, a, bb) - Cv.z;
            y15 += (idx >= 15 ? B.y : 0.f) + (idx >= 16 ? B.z : 0.f);
            m = fmaxf(m, y15);
            { int j = idx - 2; j = j > 14 ? 14 : j;
              float v = base + A.w - tb[16 + j];
              m = (idx >= 3) ? fmaxf(m, v) : m; }
            { float v = base + B.x - tb[(idx >= 2 && idx <= 15) ? (idx-1) : 1];
              m = (idx >= 2 && idx <= 15) ? fmaxf(m, v) : m; }
            { float v = base + B.y - tb[(idx >= 1 && idx <= 14) ? idx : 1];
              m = (idx >= 1 && idx <= 14) ? fmaxf(m, v) : m; }
            { int j = idx + 1; j = j < 1 ? 1 : j;
              float v = base - tb[32 + (j > 14 ? 14 : j)];
              m = (idx <= 13) ? fmaxf(m, v) : m; }
            h[ch] = fmaxf(m, 0.f);
        }
        float g[8];
        {
            const float4* bj4 = (const float4*)&Wl[300];
            float4 bj0 = bj4[0], bj1 = bj4[1];
            float bj[8] = {bj0.x,bj0.y,bj0.z,bj0.w,bj1.x,bj1.y,bj1.z,bj1.w};
            #pragma unroll
            for (int j = 0; j < 8; ++j) {
                const float4* wj = (const float4*)&Wl[140 + j*20];
                float4 q0=wj[0], q1=wj[1], q2=wj[2], q3=wj[3], q4=wj[4];
                float tt = bj[j];
                tt += q0.x*h[0]  + q0.y*h[1]  + q0.z*h[2]  + q0.w*h[3];
                tt += q1.x*h[4]  + q1.y*h[5]  + q1.z*h[6]  + q1.w*h[7];
                tt += q2.x*h[8]  + q2.y*h[9]  + q2.z*h[10] + q2.w*h[11];
                tt += q3.x*h[12] + q3.y*h[13] + q3.z*h[14] + q3.w*h[15];
                tt += q4.x*h[16] + q4.y*h[17] + q4.z*h[18] + q4.w*h[19];
                g[j] = fmaxf(tt, 0.f);
            }
        }
        float w2v[4];
        {
            const float4* bl4 = (const float4*)&Wl[340];
            float4 bl = bl4[0];
            float blv[4] = {bl.x, bl.y, bl.z, bl.w};
            #pragma unroll
            for (int l = 0; l < 4; ++l) {
                const float4* wl = (const float4*)&Wl[308 + l*8];
                float4 r0 = wl[0], r1 = wl[1];
                float tt = blv[l];
                tt += r0.x*g[0] + r0.y*g[1] + r0.z*g[2] + r0.w*g[3];
                tt += r1.x*g[4] + r1.y*g[5] + r1.z*g[6] + r1.w*g[7];
                w2v[l] = fmaxf(tt, 0.f);
            }
        }
        __half2 p01 = __floats2half2_rn(w2v[0], w2v[1]);
        __half2 p23 = __floats2half2_rn(w2v[2], w2v[3]);
        uint2 pk;
        pk.x = *(unsigned*)&p01;
        pk.y = *(unsigned*)&p23;
        tmp[(size_t)lo + i] = pk;   // pw2 aliases tmp (per-bucket in-place)
    }
}

// ---------------- K4: gather layer 1 (sequential streams) + fused node_prep2 ----
__global__ __launch_bounds__(256) void gather1_fused(
    const int* __restrict__ off, const int* __restrict__ deg,
    const unsigned* __restrict__ fin, const uint2* __restrict__ pw1,
    const __half* __restrict__ x_h, const float* __restrict__ h1,
    const float* __restrict__ theta1,
    const float* __restrict__ root2, const float* __restrict__ theta2,
    const float* __restrict__ bias2,
    float* __restrict__ o2, __half* __restrict__ P2h, int N)
{
    __shared__ float th[4 * 64 * 21];
    __shared__ float w2s[200];
    __shared__ float w2b[2];
    int tid = threadIdx.x;
    for (int i = tid; i < 5120; i += 256) {
        int l = i / 1280, f = (i / 20) % 64, h = i % 20;
        th[(l*64 + f)*21 + h] = theta1[i];
    }
    for (int i = tid; i < 200; i += 256) {
        int o = i / 20, h = i % 20;
        float v;
        if (o < 2) v = root2[h*2 + o];
        else { int l = (o-2) >> 1, jj = (o-2) & 1; v = theta2[l*40 + h*2 + jj]; }
        w2s[i] = v;
    }
    if (tid < 2) w2b[tid] = bias2[tid];
    __syncthreads();
    int t = blockIdx.x * 256 + tid;
    int n = t >> 3, q = t & 7;
    if (n >= N) return;
    int s = off[n];
    int c = deg[n];
    const unsigned* fn = fin + s;
    const uint2* fw = pw1 + s;
    float acc[4][8];
    #pragma unroll
    for (int l = 0; l < 4; ++l)
        #pragma unroll
        for (int j = 0; j < 8; ++j) acc[l][j] = 0.f;
    int pairs = c >> 1;
    for (int i = 0; i < pairs; ++i) {
        unsigned nbr1 = fn[2*i], nbr2 = fn[2*i + 1];
        uint2 k1 = fw[2*i], k2 = fw[2*i + 1];
        __half2 a01 = *(__half2*)&k1.x, a23 = *(__half2*)&k1.y;
        __half2 b01 = *(__half2*)&k2.x, b23 = *(__half2*)&k2.y;
        float2 f0 = __half22float2(a01), f1 = __half22float2(a23);
        float2 g0 = __half22float2(b01), g1 = __half22float2(b23);
        uint4 hx1 = *(const uint4*)(x_h + (size_t)nbr1*64 + q*8);
        uint4 hx2 = *(const uint4*)(x_h + (size_t)nbr2*64 + q*8);
        const __half* hp1 = (const __half*)&hx1;
        const __half* hp2 = (const __half*)&hx2;
        #pragma unroll
        for (int j2 = 0; j2 < 8; ++j2) {
            float xa = __half2float(hp1[j2]);
            float xb = __half2float(hp2[j2]);
            acc[0][j2] += f0.x * xa + g0.x * xb;
            acc[1][j2] += f0.y * xa + g0.y * xb;
            acc[2][j2] += f1.x * xa + g1.x * xb;
            acc[3][j2] += f1.y * xa + g1.y * xb;
        }
    }
    if (c & 1) {
        int i0 = c - 1;
        unsigned nbr1 = fn[i0];
        uint2 k1 = fw[i0];
        __half2 a01 = *(__half2*)&k1.x, a23 = *(__half2*)&k1.y;
        float2 f0 = __half22float2(a01), f1 = __half22float2(a23);
        uint4 hx1 = *(const uint4*)(x_h + (size_t)nbr1*64 + q*8);
        const __half* hp1 = (const __half*)&hx1;
        #pragma unroll
        for (int j2 = 0; j2 < 8; ++j2) {
            float xa = __half2float(hp1[j2]);
            acc[0][j2] += f0.x * xa;
            acc[1][j2] += f0.y * xa;
            acc[2][j2] += f1.x * xa;
            acc[3][j2] += f1.y * xa;
        }
    }
    float p[20];
    #pragma unroll
    for (int h = 0; h < 20; ++h) p[h] = 0.f;
    #pragma unroll
    for (int l = 0; l < 4; ++l) {
        #pragma unroll
        for (int j2 = 0; j2 < 8; ++j2) {
            float a = acc[l][j2];
            int base = ((l << 6) + (q << 3) + j2) * 21;
            #pragma unroll
            for (int h = 0; h < 20; ++h) p[h] += a * th[base + h];
        }
    }
    #pragma unroll
    for (int m = 1; m < 8; m <<= 1) {
        #pragma unroll
        for (int h = 0; h < 20; ++h) p[h] += __shfl_xor(p[h], m, 64);
    }
    const float4* hb = (const float4*)(h1 + (size_t)n*20);
    float hv[20];
    #pragma unroll
    for (int qq = 0; qq < 5; ++qq) {
        float4 v = hb[qq];
        hv[qq*4+0] = fmaxf(p[qq*4+0] + v.x, 0.f);
        hv[qq*4+1] = fmaxf(p[qq*4+1] + v.y, 0.f);
        hv[qq*4+2] = fmaxf(p[qq*4+2] + v.z, 0.f);
        hv[qq*4+3] = fmaxf(p[qq*4+3] + v.w, 0.f);
    }
    for (int o = q; o < 10; o += 8) {
        float v = (o < 2) ? w2b[o] : 0.f;
        #pragma unroll
        for (int h = 0; h < 20; ++h) v += hv[h] * w2s[o*20 + h];
        if (o < 2) o2[(size_t)n*2 + o] = v;
        else       P2h[(size_t)n*8 + (o - 2)] = __float2half(v);
    }
}

// ---------------- K5: gather layer 2 (streams + resident P2h) + log_softmax -----
__global__ __launch_bounds__(256) void gather2_lsm_kernel(
    const int* __restrict__ off, const int* __restrict__ deg,
    const unsigned* __restrict__ fin, const uint2* __restrict__ pw2,
    const __half* __restrict__ P2h, const float* __restrict__ o2,
    float* __restrict__ out, int N)
{
    int t = blockIdx.x * 256 + threadIdx.x;
    int n = t >> 3, r = t & 7;
    if (n >= N) return;
    int s = off[n];
    int c = deg[n];
    float o0 = 0.f, o1 = 0.f;
    for (int i = r; i < c; i += 8) {
        unsigned nbr = fin[s + i];
        uint2 k = pw2[s + i];
        __half2 a01 = *(__half2*)&k.x, a23 = *(__half2*)&k.y;
        float2 w01 = __half22float2(a01), w23 = __half22float2(a23);
        uint4 hx = *(const uint4*)(P2h + (size_t)nbr * 8);
        const __half* ph = (const __half*)&hx;
        o0 += w01.x*__half2float(ph[0]) + w01.y*__half2float(ph[2])
            + w23.x*__half2float(ph[4]) + w23.y*__half2float(ph[6]);
        o1 += w01.x*__half2float(ph[1]) + w01.y*__half2float(ph[3])
            + w23.x*__half2float(ph[5]) + w23.y*__half2float(ph[7]);
    }
    #pragma unroll
    for (int m = 1; m < 8; m <<= 1) {
        o0 += __shfl_xor(o0, m, 64);
        o1 += __shfl_xor(o1, m, 64);
    }
    if (r == 0) {
        o0 += o2[(size_t)n*2];
        o1 += o2[(size_t)n*2 + 1];
        float mx = fmaxf(o0, o1);
        float lse = mx + logf(expf(o0 - mx) + expf(o1 - mx));
        out[(size_t)n*2]     = o0 - lse;
        out[(size_t)n*2 + 1] = o1 - lse;
    }
}

// ================= Fallback path (atomic scatter, R1-style) =====================
__global__ __launch_bounds__(256) void node_prep1(
    const float* __restrict__ x, const float* __restrict__ root1,
    const float* __restrict__ theta1, const float* __restrict__ bias1,
    float* __restrict__ h1, float* __restrict__ P1, int N)
{
    __shared__ float Ws[64 * 100];
    __shared__ float xs[8 * 64];
    __shared__ float sb[20];
    int tid = threadIdx.x;
    for (int i = tid; i < 6400; i += 256) {
        int f = i / 100, c = i % 100;
        float v;
        if (c < 20) v = root1[f*20 + c];
        else { int l = (c-20)/20, hh = (c-20)%20; v = theta1[l*1280 + f*20 + hh]; }
        Ws[i] = v;
    }
    if (tid < 20) sb[tid] = bias1[tid];
    int nb = blockIdx.x * 8;
    for (int i = tid; i < 512; i += 256) {
        int nl = i >> 6, f = i & 63;
        int n = nb + nl;
        xs[i] = (n < N) ? x[(size_t)n*64 + f] : 0.f;
    }
    __syncthreads();
    for (int i = tid; i < 800; i += 256) {
        int nl = i / 100, c = i % 100;
        int n = nb + nl;
        if (n >= N) continue;
        float acc = 0.f;
        #pragma unroll 16
        for (int f = 0; f < 64; ++f) acc += xs[nl*64 + f] * Ws[f*100 + c];
        if (c < 20) h1[(size_t)n*20 + c] = acc + sb[c];
        else        P1[(size_t)n*80 + (c - 20)] = acc;
    }
}

__global__ __launch_bounds__(256) void edge_scatter1(
    const int* __restrict__ ei, const float4* __restrict__ wedge1,
    const float4* __restrict__ P1, float* __restrict__ h1, int E)
{
    int e = blockIdx.x * 256 + threadIdx.x;
    if (e >= E) return;
    int s = ei[e], d = ei[E + e];
    float4 w = wedge1[e];
    const float4* Ps = P1 + (size_t)s * 20;
    const float4* Pd = P1 + (size_t)d * 20;
    float* Hs = h1 + (size_t)s * 20;
    float* Hd = h1 + (size_t)d * 20;
    #pragma unroll
    for (int q = 0; q < 5; ++q) {
        float4 a0 = Ps[q], a1 = Ps[5+q], a2 = Ps[10+q], a3 = Ps[15+q];
        atomicAdd(Hd + q*4 + 0, w.x*a0.x + w.y*a1.x + w.z*a2.x + w.w*a3.x);
        atomicAdd(Hd + q*4 + 1, w.x*a0.y + w.y*a1.y + w.z*a2.y + w.w*a3.y);
        atomicAdd(Hd + q*4 + 2, w.x*a0.z + w.y*a1.z + w.z*a2.z + w.w*a3.z);
        atomicAdd(Hd + q*4 + 3, w.x*a0.w + w.y*a1.w + w.z*a2.w + w.w*a3.w);
        float4 b0 = Pd[q], b1 = Pd[5+q], b2 = Pd[10+q], b3 = Pd[15+q];
        atomicAdd(Hs + q*4 + 0, w.x*b0.x + w.y*b1.x + w.z*b2.x + w.w*b3.x);
        atomicAdd(Hs + q*4 + 1, w.x*b0.y + w.y*b1.y + w.z*b2.y + w.w*b3.y);
        atomicAdd(Hs + q*4 + 2, w.x*b0.z + w.y*b1.z + w.z*b2.z + w.w*b3.z);
        atomicAdd(Hs + q*4 + 3, w.x*b0.w + w.y*b1.w + w.z*b2.w + w.w*b3.w);
    }
}

__global__ __launch_bounds__(256) void node_prep2(
    const float* __restrict__ h1, const float* __restrict__ root2,
    const float* __restrict__ theta2, const float* __restrict__ bias2,
    float* __restrict__ out2, float* __restrict__ P2, int N)
{
    __shared__ float sr[40], st[160], sb2[2];
    int tid = threadIdx.x;
    if (tid < 40) sr[tid] = root2[tid];
    if (tid >= 64 && tid < 224) st[tid - 64] = theta2[tid - 64];
    if (tid < 2) sb2[tid] = bias2[tid];
    __syncthreads();
    int n = blockIdx.x * 256 + tid;
    if (n >= N) return;
    float hv[20];
    const float4* hp = (const float4*)(h1 + (size_t)n * 20);
    #pragma unroll
    for (int q = 0; q < 5; ++q) {
        float4 v = hp[q];
        hv[q*4+0] = fmaxf(v.x, 0.f);
        hv[q*4+1] = fmaxf(v.y, 0.f);
        hv[q*4+2] = fmaxf(v.z, 0.f);
        hv[q*4+3] = fmaxf(v.w, 0.f);
    }
    float o0 = sb2[0], o1 = sb2[1];
    #pragma unroll
    for (int h = 0; h < 20; ++h) { o0 += hv[h]*sr[h*2]; o1 += hv[h]*sr[h*2+1]; }
    out2[(size_t)n*2 + 0] = o0;
    out2[(size_t)n*2 + 1] = o1;
    #pragma unroll
    for (int l = 0; l < 4; ++l) {
        float p0 = 0.f, p1 = 0.f;
        #pragma unroll
        for (int h = 0; h < 20; ++h) {
            p0 += hv[h]*st[l*40 + h*2];
            p1 += hv[h]*st[l*40 + h*2 + 1];
        }
        P2[(size_t)n*8 + l*2 + 0] = p0;
        P2[(size_t)n*8 + l*2 + 1] = p1;
    }
}

__global__ __launch_bounds__(256) void edge_scatter2(
    const int* __restrict__ ei, const float4* __restrict__ wedge2,
    const float4* __restrict__ P2, float* __restrict__ out2, int E)
{
    int e = blockIdx.x * 256 + threadIdx.x;
    if (e >= E) return;
    int s = ei[e], d = ei[E + e];
    float4 w = wedge2[e];
    float4 pa = P2[(size_t)s*2], pb = P2[(size_t)s*2 + 1];
    float y0 = w.x*pa.x + w.y*pa.z + w.z*pb.x + w.w*pb.z;
    float y1 = w.x*pa.y + w.y*pa.w + w.z*pb.y + w.w*pb.w;
    atomicAdd(out2 + (size_t)d*2 + 0, y0);
    atomicAdd(out2 + (size_t)d*2 + 1, y1);
    float4 qa = P2[(size_t)d*2], qb = P2[(size_t)d*2 + 1];
    float z0 = w.x*qa.x + w.y*qa.z + w.z*qb.x + w.w*qb.z;
    float z1 = w.x*qa.y + w.y*qa.w + w.z*qb.y + w.w*qb.w;
    atomicAdd(out2 + (size_t)s*2 + 0, z0);
    atomicAdd(out2 + (size_t)s*2 + 1, z1);
}

__global__ __launch_bounds__(256) void logsoftmax_k(
    const float* __restrict__ out2, float* __restrict__ out, int N)
{
    int n = blockIdx.x * 256 + threadIdx.x;
    if (n >= N) return;
    float o0 = out2[(size_t)n*2], o1 = out2[(size_t)n*2 + 1];
    float m = fmaxf(o0, o1);
    float lse = m + logf(expf(o0 - m) + expf(o1 - m));
    out[(size_t)n*2]     = o0 - lse;
    out[(size_t)n*2 + 1] = o1 - lse;
}

extern "C" void kernel_launch(void* const* d_in, const int* in_sizes, int n_in,
                              void* d_out, int out_size, void* d_ws, size_t ws_size,
                              hipStream_t stream)
{
    const float* x     = (const float*)d_in[0];
    const int*   ei    = (const int*)d_in[1];
    const float* attr  = (const float*)d_in[2];
    const float* cut   = (const float*)d_in[3];
    const float* cw1   = (const float*)d_in[4];
    const float* cb1   = (const float*)d_in[5];
    const float* f1w1  = (const float*)d_in[6];
    const float* f1b1  = (const float*)d_in[7];
    const float* f2w1  = (const float*)d_in[8];
    const float* f2b1  = (const float*)d_in[9];
    const float* th1   = (const float*)d_in[10];
    const float* rt1   = (const float*)d_in[11];
    const float* bs1   = (const float*)d_in[12];
    const float* cw2   = (const float*)d_in[13];
    const float* cb2   = (const float*)d_in[14];
    const float* f1w2  = (const float*)d_in[15];
    const float* f1b2  = (const float*)d_in[16];
    const float* f2w2  = (const float*)d_in[17];
    const float* f2b2  = (const float*)d_in[18];
    const float* th2   = (const float*)d_in[19];
    const float* rt2   = (const float*)d_in[20];
    const float* bs2   = (const float*)d_in[21];

    const int N = in_sizes[0] / 64;
    const int E = in_sizes[1] / 2;
    const int M = 2 * E;
    const int NB = (N + 127) >> SHIFT;
    const size_t NBB = (size_t)NB * BCAP;

    // ---- tier-A workspace layout (words); total ~108.9 MB ----
    size_t W = 0;
    float* ws = (float*)d_ws;
    uint2* wedge1h = (uint2*)(ws + W);     W += (size_t)E * 2;
    uint2* tmp     = (uint2*)(ws + W);     W += NBB * 2;   // entries -> pw2 (alias)
    unsigned* fin  = (unsigned*)(ws + W);  W += NBB;
    uint2* pw1     = (uint2*)(ws + W);     W += NBB * 2;
    int* off       = (int*)(ws + W);       W += N;
    int* deg       = (int*)(ws + W);       W += N;
    int* bcur      = (int*)(ws + W);       W += NB;
    W = (W + 31) & ~(size_t)31;
    __half* x_h = (__half*)(ws + W);                  // 32N words
    float*  h1  = ws + W + (size_t)N * 32;            // 20N
    __half* P2h = (__half*)(ws + W + (size_t)N * 52); // 4N words
    float*  o2  = ws + W + (size_t)N * 56;            // 2N
    size_t need_new = W + (size_t)N * 58;

    bool okNew = (NB <= NB_MAX) && (E <= (1 << 21)) && (N <= (1 << 17)) &&
                 (ws_size / 4 >= need_new);

    if (okNew) {
        const int FB = (E + 255) / 256;
        const int PB = (N * 8 + 255) / 256;
        filter_prep_kernel<<<FB + PB, 256, 0, stream>>>(
            attr, cut, cw1, cb1, f1w1, f1b1, f2w1, f2b1,
            cw2, cb2, f1w2, f1b2, f2w2, f2b2,
            wedge1h, nullptr, nullptr, bcur, NB, E,
            x, rt1, bs1, h1, x_h, N, FB);
        passB_kernel<<<(M + CHUNKB - 1) / CHUNKB, 256, 0, stream>>>(
            ei, bcur, tmp, E, M, NB);
        passC_kernel<<<NB, 256, 0, stream>>>(
            tmp, bcur, wedge1h, attr, cut,
            cw2, cb2, f1w2, f1b2, f2w2, f2b2,
            fin, pw1, off, deg, E, N);
        gather1_fused<<<(N * 8 + 255) / 256, 256, 0, stream>>>(
            off, deg, fin, pw1, x_h, h1,
            th1, rt2, th2, bs2, o2, P2h, N);
        gather2_lsm_kernel<<<(N * 8 + 255) / 256, 256, 0, stream>>>(
            off, deg, fin, tmp /*pw2*/, P2h, o2, (float*)d_out, N);
    } else {
        // Fallback: atomic scatter (correct but slow). Independent layout.
        float* fw1 = ws;                           // 4E
        float* fw2 = fw1 + (size_t)E * 4;          // 4E
        float* P1  = fw2 + (size_t)E * 4;          // 80N (also dummy wedge1h)
        float* fh1 = P1  + (size_t)N * 80;         // 20N
        float* fP2 = fh1 + (size_t)N * 20;         // 8N
        float* fo2 = fP2 + (size_t)N * 8;          // 2N
        int*   fbc = (int*)(fo2 + (size_t)N * 2);  // NB (dummy bcur)
        const int FB = (E + 255) / 256;
        filter_prep_kernel<<<FB, 256, 0, stream>>>(
            attr, cut, cw1, cb1, f1w1, f1b1, f2w1, f2b1,
            cw2, cb2, f1w2, f1b2, f2w2, f2b2,
            (uint2*)P1, (float4*)fw1, (float4*)fw2, fbc,
            NB <= NB_MAX ? NB : NB_MAX, E,
            x, rt1, bs1, fh1, (__half*)fP2, N, FB);
        node_prep1<<<(N + 7) / 8, 256, 0, stream>>>(x, rt1, th1, bs1, fh1, P1, N);
        edge_scatter1<<<(E + 255) / 256, 256, 0, stream>>>(
            ei, (const float4*)fw1, (const float4*)P1, fh1, E);
        node_prep2<<<(N + 255) / 256, 256, 0, stream>>>(fh1, rt2, th2, bs2, fo2, fP2, N);
        edge_scatter2<<<(E + 255) / 256, 256, 0, stream>>>(
            ei, (const float4*)fw2, (const float4*)fP2, fo2, E);
        logsoftmax_k<<<(N + 255) / 256, 256, 0, stream>>>(fo2, (float*)d_out, N);
    }
}

// Round 13
// 698.600 us; speedup vs baseline: 1.3060x; 1.3060x over previous
//
#include <hip/hip_runtime.h>
#include <hip/hip_fp16.h>
#include <math.h>

// Problem constants: F_IN=64, K=16, C=20, L=4, H1=20, H2=2
// N=100k nodes, E=1.6M undirected edges, M=2E=3.2M directed entries.
//
// R10-R12 lesson: the analytic filter eval compiles to 252 VGPR whenever it
// sits inside a multi-iteration loop (compiler pipelines it), 32 VGPR as a
// once-per-thread body. R13: eval lives ONLY in the filter kernel (both
// layers, fp16-packed). passC = sort-only (pos16 permutation in LDS, 64 KB ->
// 2 blk/CU) + payload copy in chunk-grouped order (quasi-seq reads, writes
// scattered only within the L2-resident 37 KB bucket slice). pw2 aliases tmp.

#define SHIFT   7
#define NB_MAX  1024
#define CHUNKB  6144
#define BCAP    4608

// ---------------- K1: filter net (both layers) + prep (block-range split) -------
// fp16 mode (w1f==null): both layers packed fp16 -> wedge1h/wedge2h.
// Fallback mode: fp32 float4 both layers -> w1f/w2f.
__global__ __launch_bounds__(256) void filter_prep_kernel(
    const float* __restrict__ attr, const float* __restrict__ cutoffs,
    const float* __restrict__ cw1, const float* __restrict__ cb1,
    const float* __restrict__ f1w1, const float* __restrict__ f1b1,
    const float* __restrict__ f2w1, const float* __restrict__ f2b1,
    const float* __restrict__ cw2, const float* __restrict__ cb2,
    const float* __restrict__ f1w2, const float* __restrict__ f1b2,
    const float* __restrict__ f2w2, const float* __restrict__ f2b2,
    uint2* __restrict__ wedge1h, uint2* __restrict__ wedge2h,
    float4* __restrict__ w1f, float4* __restrict__ w2f,
    int* __restrict__ bcur, int NB, int E,
    const float* __restrict__ x, const float* __restrict__ root1,
    const float* __restrict__ bias1, float* __restrict__ h1,
    __half* __restrict__ x_h, int N, int FB)
{
    int tid = threadIdx.x;
    if ((int)blockIdx.x >= FB) {
        __shared__ float r1s[64 * 21];
        __shared__ float sb[20];
        for (int i = tid; i < 1280; i += 256) {
            int f = i / 20, h = i % 20;
            r1s[f*21 + h] = root1[i];
        }
        if (tid < 20) sb[tid] = bias1[tid];
        __syncthreads();
        int t = ((int)blockIdx.x - FB) * 256 + tid;
        int n = t >> 3, q = t & 7;
        if (n >= N) return;
        const float4* xr = (const float4*)(x + (size_t)n*64 + q*8);
        float4 va = xr[0], vb = xr[1];
        float xf[8] = {va.x, va.y, va.z, va.w, vb.x, vb.y, vb.z, vb.w};
        __half hh[8];
        #pragma unroll
        for (int j = 0; j < 8; ++j) hh[j] = __float2half(xf[j]);
        *(uint4*)(x_h + (size_t)n*64 + q*8) = *(const uint4*)hh;
        float p[20];
        #pragma unroll
        for (int h = 0; h < 20; ++h) p[h] = 0.f;
        #pragma unroll
        for (int j = 0; j < 8; ++j) {
            float xv = xf[j];
            int base = (q*8 + j) * 21;
            #pragma unroll
            for (int h = 0; h < 20; ++h) p[h] += xv * r1s[base + h];
        }
        #pragma unroll
        for (int m = 1; m < 8; m <<= 1) {
            #pragma unroll
            for (int h = 0; h < 20; ++h) p[h] += __shfl_xor(p[h], m, 64);
        }
        if (q < 5) {
            float4 o;
            o.x = p[q*4+0] + sb[q*4+0];
            o.y = p[q*4+1] + sb[q*4+1];
            o.z = p[q*4+2] + sb[q*4+2];
            o.w = p[q*4+3] + sb[q*4+3];
            *(float4*)(h1 + (size_t)n*20 + q*4) = o;
        }
        return;
    }
    // ---------------- filter body ----------------
    __shared__ float s_cut[16];
    __shared__ float s_w[2][344];
    __shared__ float tab[2 * 20 * 64];
    int gb = blockIdx.x * 256 + tid;
    if (gb < NB) bcur[gb] = gb * BCAP;
    if (tid < 16) s_cut[tid] = cutoffs[tid];
    for (int i = tid; i < 344; i += 256) {
        float v1, v2;
        if (i < 120)      { v1 = cw1[i];       v2 = cw2[i]; }
        else if (i < 140) { v1 = cb1[i-120];   v2 = cb2[i-120]; }
        else if (i < 300) { v1 = f1w1[i-140];  v2 = f1w2[i-140]; }
        else if (i < 308) { v1 = f1b1[i-300];  v2 = f1b2[i-300]; }
        else if (i < 340) { v1 = f2w1[i-308];  v2 = f2w2[i-308]; }
        else              { v1 = f2b1[i-340];  v2 = f2b2[i-340]; }
        s_w[0][i] = v1; s_w[1][i] = v2;
    }
    __syncthreads();
    if (tid < 40) {
        int l = tid / 20, ch = tid % 20;
        const float* W = s_w[l];
        float w00 = W[ch*6+0], w01 = W[ch*6+1], w02 = W[ch*6+2];
        float w10 = W[ch*6+3], w11 = W[ch*6+4], w12 = W[ch*6+5];
        float b = W[120 + ch];
        float* tb = &tab[(l*20 + ch) * 64];
        tb[0]  = w01*s_cut[0]  + w02*s_cut[1];
        for (int k = 1; k <= 14; ++k)
            tb[k] = w00*s_cut[k-1] + w01*s_cut[k] + w02*s_cut[k+1];
        tb[15] = w00*s_cut[14] + w01*s_cut[15];
        float pm = tb[1]; tb[16+1] = pm;
        for (int j = 2; j <= 14; ++j) { pm = fminf(pm, tb[j]); tb[16+j] = pm; }
        float qm = tb[14]; tb[32+14] = qm;
        for (int j = 13; j >= 1; --j) { qm = fminf(qm, tb[j]); tb[32+j] = qm; }
        tb[48] = w00 + w01 + w02;
        tb[49] = w01 + w02;
        tb[50] = w00 + w01;
        tb[51] = w10 + w11 + w12;
        tb[52] = w10 + w11;
        tb[53] = w10;
        tb[54] = w11;
        tb[55] = w12;
        tb[56] = b;
        tb[57] = tb[0];
        tb[58] = tb[15];
        tb[59] = 0.f;
    }
    __syncthreads();
    int e = gb;
    if (e >= E) return;

    float a = attr[e];
    int idx = 0;
    #pragma unroll
    for (int k = 0; k < 16; ++k) idx += (a > s_cut[k]) ? 1 : 0;

    #pragma unroll
    for (int layer = 0; layer < 2; ++layer) {
        const float* W = s_w[layer];
        float h[20];
        #pragma unroll
        for (int c = 0; c < 20; ++c) {
            const float* tb = &tab[(layer*20 + c) * 64];
            const float4* tb4 = (const float4*)tb;
            float4 A  = tb4[12];
            float4 B  = tb4[13];
            float4 Cv = tb4[14];
            float b = Cv.x;
            float base = fmaf(A.x, a, b);
            float y0 = fmaf(A.y, a, b) - Cv.y;
            y0 += (idx >= 1 ? B.z : 0.f) + (idx >= 2 ? B.w : 0.f);
            float m = y0;
            float y15 = fmaf(A.z, a, b) - Cv.z;
            y15 += (idx >= 15 ? B.y : 0.f) + (idx >= 16 ? B.z : 0.f);
            m = fmaxf(m, y15);
            { int j = idx - 2; j = j > 14 ? 14 : j;
              float v = base + A.w - tb[16 + j];
              m = (idx >= 3) ? fmaxf(m, v) : m; }
            { float v = base + B.x - tb[(idx >= 2 && idx <= 15) ? (idx-1) : 1];
              m = (idx >= 2 && idx <= 15) ? fmaxf(m, v) : m; }
            { float v = base + B.y - tb[(idx >= 1 && idx <= 14) ? idx : 1];
              m = (idx >= 1 && idx <= 14) ? fmaxf(m, v) : m; }
            { int j = idx + 1; j = j < 1 ? 1 : j;
              float v = base - tb[32 + (j > 14 ? 14 : j)];
              m = (idx <= 13) ? fmaxf(m, v) : m; }
            h[c] = fmaxf(m, 0.f);
        }
        float g[8];
        {
            const float4* bj4 = (const float4*)&W[300];
            float4 bj0 = bj4[0], bj1 = bj4[1];
            float bj[8] = {bj0.x,bj0.y,bj0.z,bj0.w,bj1.x,bj1.y,bj1.z,bj1.w};
            #pragma unroll
            for (int j = 0; j < 8; ++j) {
                const float4* wj = (const float4*)&W[140 + j*20];
                float4 q0=wj[0], q1=wj[1], q2=wj[2], q3=wj[3], q4=wj[4];
                float t = bj[j];
                t += q0.x*h[0]  + q0.y*h[1]  + q0.z*h[2]  + q0.w*h[3];
                t += q1.x*h[4]  + q1.y*h[5]  + q1.z*h[6]  + q1.w*h[7];
                t += q2.x*h[8]  + q2.y*h[9]  + q2.z*h[10] + q2.w*h[11];
                t += q3.x*h[12] + q3.y*h[13] + q3.z*h[14] + q3.w*h[15];
                t += q4.x*h[16] + q4.y*h[17] + q4.z*h[18] + q4.w*h[19];
                g[j] = fmaxf(t, 0.f);
            }
        }
        float wv[4];
        {
            const float4* bl4 = (const float4*)&W[340];
            float4 bl = bl4[0];
            float blv[4] = {bl.x, bl.y, bl.z, bl.w};
            #pragma unroll
            for (int l = 0; l < 4; ++l) {
                const float4* wl = (const float4*)&W[308 + l*8];
                float4 r0 = wl[0], r1 = wl[1];
                float t = blv[l];
                t += r0.x*g[0] + r0.y*g[1] + r0.z*g[2] + r0.w*g[3];
                t += r1.x*g[4] + r1.y*g[5] + r1.z*g[6] + r1.w*g[7];
                wv[l] = fmaxf(t, 0.f);
            }
        }
        if (w1f != nullptr) {
            float4 wo = make_float4(wv[0], wv[1], wv[2], wv[3]);
            if (layer == 0) w1f[e] = wo; else w2f[e] = wo;
        } else {
            __half2 p01 = __floats2half2_rn(wv[0], wv[1]);
            __half2 p23 = __floats2half2_rn(wv[2], wv[3]);
            uint2 pk;
            pk.x = *(unsigned*)&p01;
            pk.y = *(unsigned*)&p23;
            if (layer == 0) wedge1h[e] = pk; else wedge2h[e] = pk;
        }
    }
}

// ---------------- K2: scatter directed entries into capacity buckets ------------
// uint2 entry: x = nbr node, y = we | own7<<22  (ei read sequentially)
__global__ __launch_bounds__(256) void passB_kernel(
    const int* __restrict__ ei, int* __restrict__ bcur, uint2* __restrict__ tmp,
    int E, int M, int NB)
{
    __shared__ int hist[NB_MAX];
    __shared__ int lbase[NB_MAX];
    __shared__ int gpos[NB_MAX];
    __shared__ int aux[256];
    __shared__ uint2 stage[CHUNKB];
    int tid = threadIdx.x;
    int start = blockIdx.x * CHUNKB;
    if (start >= M) return;
    int cnt = M - start; if (cnt > CHUNKB) cnt = CHUNKB;
    for (int i = tid; i < NB_MAX; i += 256) hist[i] = 0;
    __syncthreads();
    for (int i = tid; i < cnt; i += 256) {
        int de = start + i;
        int own = ei[de < E ? de + E : de - E];
        atomicAdd(&hist[own >> SHIFT], 1);
    }
    __syncthreads();
    {
        int t4 = tid * 4;
        int a0 = hist[t4], a1 = hist[t4+1], a2 = hist[t4+2], a3 = hist[t4+3];
        aux[tid] = a0 + a1 + a2 + a3;
        __syncthreads();
        for (int off = 1; off < 256; off <<= 1) {
            int v = (tid >= off) ? aux[tid - off] : 0;
            __syncthreads();
            aux[tid] += v;
            __syncthreads();
        }
        int te = (tid == 0) ? 0 : aux[tid - 1];
        lbase[t4]   = te;
        lbase[t4+1] = te + a0;
        lbase[t4+2] = te + a0 + a1;
        lbase[t4+3] = te + a0 + a1 + a2;
    }
    __syncthreads();
    for (int b = tid; b < NB; b += 256) {
        int cb = hist[b];
        gpos[b] = cb ? atomicAdd(&bcur[b], cb) : 0;
    }
    __syncthreads();
    for (int i = tid; i < NB_MAX; i += 256) hist[i] = 0;
    __syncthreads();
    for (int i = tid; i < cnt; i += 256) {
        int de = start + i;
        int j = de < E ? de : de - E;
        int own = ei[de < E ? de + E : de - E];
        unsigned nbr = (unsigned)ei[de];
        int b = own >> SHIFT;
        int p = atomicAdd(&hist[b], 1);
        stage[lbase[b] + p] = make_uint2(nbr, (unsigned)j | ((unsigned)(own & 127) << 22));
    }
    __syncthreads();
    int wave = tid >> 6, lane = tid & 63;
    for (int b = wave; b < NB; b += 4) {
        int n_b = hist[b];
        if (!n_b) continue;
        int lo = lbase[b], g = gpos[b];
        int lim = (b + 1) * BCAP;
        for (int k = lane; k < n_b; k += 64) {
            if (g + k < lim) tmp[(size_t)g + k] = stage[lo + k];
        }
    }
}

// ---------------- K3: class-sort (pos16 permutation) + payload copy -------------
// Sort key = own7*16 + (nbr>>13). No eval here (VGPR stays low). Payload reads
// happen in ORIGINAL chunk-grouped order (quasi-sequential); writes scatter
// only within the bucket's 18-37 KB slices (L2-resident). pw2 aliases tmp.
__global__ __launch_bounds__(256) void passC_kernel(
    uint2* __restrict__ tmp /* in: entries, out: pw2 */, const int* __restrict__ bcur,
    const uint2* __restrict__ wedge1h, const uint2* __restrict__ wedge2h,
    unsigned* __restrict__ fin, uint2* __restrict__ pw1,
    int* __restrict__ off, int* __restrict__ deg, int N)
{
    __shared__ uint2 ent[BCAP];
    __shared__ unsigned short pos16[BCAP];
    __shared__ int h2[2048];
    __shared__ int e2p[2048];
    __shared__ int aux[256];
    int tid = threadIdx.x;
    int b = blockIdx.x;
    int lo = b * BCAP;
    int cnt = bcur[b] - lo;
    if (cnt > BCAP) cnt = BCAP;
    for (int i = tid; i < cnt; i += 256) ent[i] = tmp[(size_t)lo + i];
    for (int i = tid; i < 2048; i += 256) h2[i] = 0;
    __syncthreads();
    for (int i = tid; i < cnt; i += 256) {
        uint2 en = ent[i];
        atomicAdd(&h2[(en.y >> 22) * 16 + ((en.x >> 13) & 15)], 1);
    }
    __syncthreads();
    {   // exclusive scan h2 -> e2p
        int base8 = tid * 8;
        int v[8]; int s = 0;
        #pragma unroll
        for (int j = 0; j < 8; ++j) { v[j] = h2[base8 + j]; s += v[j]; }
        aux[tid] = s;
        __syncthreads();
        for (int o = 1; o < 256; o <<= 1) {
            int t = (tid >= o) ? aux[tid - o] : 0;
            __syncthreads();
            aux[tid] += t;
            __syncthreads();
        }
        int excl = (tid == 0) ? 0 : aux[tid - 1];
        int run = 0;
        #pragma unroll
        for (int j = 0; j < 8; ++j) { e2p[base8 + j] = excl + run; run += v[j]; }
    }
    __syncthreads();
    if (tid < 128) {
        int base = e2p[tid * 16];
        int next = (tid < 127) ? e2p[(tid + 1) * 16] : cnt;
        int node = (b << SHIFT) + tid;
        if (node < N) { off[node] = lo + base; deg[node] = next - base; }
    }
    for (int i = tid; i < 2048; i += 256) h2[i] = 0;  // reuse as cursor
    __syncthreads();
    for (int i = tid; i < cnt; i += 256) {
        uint2 en = ent[i];
        int key = (en.y >> 22) * 16 + ((en.x >> 13) & 15);
        int p = atomicAdd(&h2[key], 1);
        pos16[i] = (unsigned short)(e2p[key] + p);
    }
    __syncthreads();
    // Payload copy: reads quasi-sequential (original order), writes L2-local.
    for (int i = tid; i < cnt; i += 256) {
        uint2 en = ent[i];
        unsigned we = en.y & 0x3FFFFFu;
        int p = pos16[i];
        uint2 k1 = wedge1h[we];
        uint2 k2 = wedge2h[we];
        fin[(size_t)lo + p] = en.x;
        pw1[(size_t)lo + p] = k1;
        tmp[(size_t)lo + p] = k2;    // pw2 aliases tmp (per-bucket, in-place)
    }
}

// ---------------- K4: gather layer 1 (sequential streams) + fused node_prep2 ----
__global__ __launch_bounds__(256) void gather1_fused(
    const int* __restrict__ off, const int* __restrict__ deg,
    const unsigned* __restrict__ fin, const uint2* __restrict__ pw1,
    const __half* __restrict__ x_h, const float* __restrict__ h1,
    const float* __restrict__ theta1,
    const float* __restrict__ root2, const float* __restrict__ theta2,
    const float* __restrict__ bias2,
    float* __restrict__ o2, __half* __restrict__ P2h, int N)
{
    __shared__ float th[4 * 64 * 21];
    __shared__ float w2s[200];
    __shared__ float w2b[2];
    int tid = threadIdx.x;
    for (int i = tid; i < 5120; i += 256) {
        int l = i / 1280, f = (i / 20) % 64, h = i % 20;
        th[(l*64 + f)*21 + h] = theta1[i];
    }
    for (int i = tid; i < 200; i += 256) {
        int o = i / 20, h = i % 20;
        float v;
        if (o < 2) v = root2[h*2 + o];
        else { int l = (o-2) >> 1, jj = (o-2) & 1; v = theta2[l*40 + h*2 + jj]; }
        w2s[i] = v;
    }
    if (tid < 2) w2b[tid] = bias2[tid];
    __syncthreads();
    int t = blockIdx.x * 256 + tid;
    int n = t >> 3, q = t & 7;
    if (n >= N) return;
    int s = off[n];
    int c = deg[n];
    const unsigned* fn = fin + s;
    const uint2* fw = pw1 + s;
    float acc[4][8];
    #pragma unroll
    for (int l = 0; l < 4; ++l)
        #pragma unroll
        for (int j = 0; j < 8; ++j) acc[l][j] = 0.f;
    int pairs = c >> 1;
    for (int i = 0; i < pairs; ++i) {
        unsigned nbr1 = fn[2*i], nbr2 = fn[2*i + 1];
        uint2 k1 = fw[2*i], k2 = fw[2*i + 1];
        __half2 a01 = *(__half2*)&k1.x, a23 = *(__half2*)&k1.y;
        __half2 b01 = *(__half2*)&k2.x, b23 = *(__half2*)&k2.y;
        float2 f0 = __half22float2(a01), f1 = __half22float2(a23);
        float2 g0 = __half22float2(b01), g1 = __half22float2(b23);
        uint4 hx1 = *(const uint4*)(x_h + (size_t)nbr1*64 + q*8);
        uint4 hx2 = *(const uint4*)(x_h + (size_t)nbr2*64 + q*8);
        const __half* hp1 = (const __half*)&hx1;
        const __half* hp2 = (const __half*)&hx2;
        #pragma unroll
        for (int j2 = 0; j2 < 8; ++j2) {
            float xa = __half2float(hp1[j2]);
            float xb = __half2float(hp2[j2]);
            acc[0][j2] += f0.x * xa + g0.x * xb;
            acc[1][j2] += f0.y * xa + g0.y * xb;
            acc[2][j2] += f1.x * xa + g1.x * xb;
            acc[3][j2] += f1.y * xa + g1.y * xb;
        }
    }
    if (c & 1) {
        int i0 = c - 1;
        unsigned nbr1 = fn[i0];
        uint2 k1 = fw[i0];
        __half2 a01 = *(__half2*)&k1.x, a23 = *(__half2*)&k1.y;
        float2 f0 = __half22float2(a01), f1 = __half22float2(a23);
        uint4 hx1 = *(const uint4*)(x_h + (size_t)nbr1*64 + q*8);
        const __half* hp1 = (const __half*)&hx1;
        #pragma unroll
        for (int j2 = 0; j2 < 8; ++j2) {
            float xa = __half2float(hp1[j2]);
            acc[0][j2] += f0.x * xa;
            acc[1][j2] += f0.y * xa;
            acc[2][j2] += f1.x * xa;
            acc[3][j2] += f1.y * xa;
        }
    }
    float p[20];
    #pragma unroll
    for (int h = 0; h < 20; ++h) p[h] = 0.f;
    #pragma unroll
    for (int l = 0; l < 4; ++l) {
        #pragma unroll
        for (int j2 = 0; j2 < 8; ++j2) {
            float a = acc[l][j2];
            int base = ((l << 6) + (q << 3) + j2) * 21;
            #pragma unroll
            for (int h = 0; h < 20; ++h) p[h] += a * th[base + h];
        }
    }
    #pragma unroll
    for (int m = 1; m < 8; m <<= 1) {
        #pragma unroll
        for (int h = 0; h < 20; ++h) p[h] += __shfl_xor(p[h], m, 64);
    }
    const float4* hb = (const float4*)(h1 + (size_t)n*20);
    float hv[20];
    #pragma unroll
    for (int qq = 0; qq < 5; ++qq) {
        float4 v = hb[qq];
        hv[qq*4+0] = fmaxf(p[qq*4+0] + v.x, 0.f);
        hv[qq*4+1] = fmaxf(p[qq*4+1] + v.y, 0.f);
        hv[qq*4+2] = fmaxf(p[qq*4+2] + v.z, 0.f);
        hv[qq*4+3] = fmaxf(p[qq*4+3] + v.w, 0.f);
    }
    for (int o = q; o < 10; o += 8) {
        float v = (o < 2) ? w2b[o] : 0.f;
        #pragma unroll
        for (int h = 0; h < 20; ++h) v += hv[h] * w2s[o*20 + h];
        if (o < 2) o2[(size_t)n*2 + o] = v;
        else       P2h[(size_t)n*8 + (o - 2)] = __float2half(v);
    }
}

// ---------------- K5: gather layer 2 (streams + resident P2h) + log_softmax -----
__global__ __launch_bounds__(256) void gather2_lsm_kernel(
    const int* __restrict__ off, const int* __restrict__ deg,
    const unsigned* __restrict__ fin, const uint2* __restrict__ pw2,
    const __half* __restrict__ P2h, const float* __restrict__ o2,
    float* __restrict__ out, int N)
{
    int t = blockIdx.x * 256 + threadIdx.x;
    int n = t >> 3, r = t & 7;
    if (n >= N) return;
    int s = off[n];
    int c = deg[n];
    float o0 = 0.f, o1 = 0.f;
    for (int i = r; i < c; i += 8) {
        unsigned nbr = fin[s + i];
        uint2 k = pw2[s + i];
        __half2 a01 = *(__half2*)&k.x, a23 = *(__half2*)&k.y;
        float2 w01 = __half22float2(a01), w23 = __half22float2(a23);
        uint4 hx = *(const uint4*)(P2h + (size_t)nbr * 8);
        const __half* ph = (const __half*)&hx;
        o0 += w01.x*__half2float(ph[0]) + w01.y*__half2float(ph[2])
            + w23.x*__half2float(ph[4]) + w23.y*__half2float(ph[6]);
        o1 += w01.x*__half2float(ph[1]) + w01.y*__half2float(ph[3])
            + w23.x*__half2float(ph[5]) + w23.y*__half2float(ph[7]);
    }
    #pragma unroll
    for (int m = 1; m < 8; m <<= 1) {
        o0 += __shfl_xor(o0, m, 64);
        o1 += __shfl_xor(o1, m, 64);
    }
    if (r == 0) {
        o0 += o2[(size_t)n*2];
        o1 += o2[(size_t)n*2 + 1];
        float mx = fmaxf(o0, o1);
        float lse = mx + logf(expf(o0 - mx) + expf(o1 - mx));
        out[(size_t)n*2]     = o0 - lse;
        out[(size_t)n*2 + 1] = o1 - lse;
    }
}

// ================= Fallback path (atomic scatter, R1-style) =====================
__global__ __launch_bounds__(256) void node_prep1(
    const float* __restrict__ x, const float* __restrict__ root1,
    const float* __restrict__ theta1, const float* __restrict__ bias1,
    float* __restrict__ h1, float* __restrict__ P1, int N)
{
    __shared__ float Ws[64 * 100];
    __shared__ float xs[8 * 64];
    __shared__ float sb[20];
    int tid = threadIdx.x;
    for (int i = tid; i < 6400; i += 256) {
        int f = i / 100, c = i % 100;
        float v;
        if (c < 20) v = root1[f*20 + c];
        else { int l = (c-20)/20, hh = (c-20)%20; v = theta1[l*1280 + f*20 + hh]; }
        Ws[i] = v;
    }
    if (tid < 20) sb[tid] = bias1[tid];
    int nb = blockIdx.x * 8;
    for (int i = tid; i < 512; i += 256) {
        int nl = i >> 6, f = i & 63;
        int n = nb + nl;
        xs[i] = (n < N) ? x[(size_t)n*64 + f] : 0.f;
    }
    __syncthreads();
    for (int i = tid; i < 800; i += 256) {
        int nl = i / 100, c = i % 100;
        int n = nb + nl;
        if (n >= N) continue;
        float acc = 0.f;
        #pragma unroll 16
        for (int f = 0; f < 64; ++f) acc += xs[nl*64 + f] * Ws[f*100 + c];
        if (c < 20) h1[(size_t)n*20 + c] = acc + sb[c];
        else        P1[(size_t)n*80 + (c - 20)] = acc;
    }
}

__global__ __launch_bounds__(256) void edge_scatter1(
    const int* __restrict__ ei, const float4* __restrict__ wedge1,
    const float4* __restrict__ P1, float* __restrict__ h1, int E)
{
    int e = blockIdx.x * 256 + threadIdx.x;
    if (e >= E) return;
    int s = ei[e], d = ei[E + e];
    float4 w = wedge1[e];
    const float4* Ps = P1 + (size_t)s * 20;
    const float4* Pd = P1 + (size_t)d * 20;
    float* Hs = h1 + (size_t)s * 20;
    float* Hd = h1 + (size_t)d * 20;
    #pragma unroll
    for (int q = 0; q < 5; ++q) {
        float4 a0 = Ps[q], a1 = Ps[5+q], a2 = Ps[10+q], a3 = Ps[15+q];
        atomicAdd(Hd + q*4 + 0, w.x*a0.x + w.y*a1.x + w.z*a2.x + w.w*a3.x);
        atomicAdd(Hd + q*4 + 1, w.x*a0.y + w.y*a1.y + w.z*a2.y + w.w*a3.y);
        atomicAdd(Hd + q*4 + 2, w.x*a0.z + w.y*a1.z + w.z*a2.z + w.w*a3.z);
        atomicAdd(Hd + q*4 + 3, w.x*a0.w + w.y*a1.w + w.z*a2.w + w.w*a3.w);
        float4 b0 = Pd[q], b1 = Pd[5+q], b2 = Pd[10+q], b3 = Pd[15+q];
        atomicAdd(Hs + q*4 + 0, w.x*b0.x + w.y*b1.x + w.z*b2.x + w.w*b3.x);
        atomicAdd(Hs + q*4 + 1, w.x*b0.y + w.y*b1.y + w.z*b2.y + w.w*b3.y);
        atomicAdd(Hs + q*4 + 2, w.x*b0.z + w.y*b1.z + w.z*b2.z + w.w*b3.z);
        atomicAdd(Hs + q*4 + 3, w.x*b0.w + w.y*b1.w + w.z*b2.w + w.w*b3.w);
    }
}

__global__ __launch_bounds__(256) void node_prep2(
    const float* __restrict__ h1, const float* __restrict__ root2,
    const float* __restrict__ theta2, const float* __restrict__ bias2,
    float* __restrict__ out2, float* __restrict__ P2, int N)
{
    __shared__ float sr[40], st[160], sb2[2];
    int tid = threadIdx.x;
    if (tid < 40) sr[tid] = root2[tid];
    if (tid >= 64 && tid < 224) st[tid - 64] = theta2[tid - 64];
    if (tid < 2) sb2[tid] = bias2[tid];
    __syncthreads();
    int n = blockIdx.x * 256 + tid;
    if (n >= N) return;
    float hv[20];
    const float4* hp = (const float4*)(h1 + (size_t)n * 20);
    #pragma unroll
    for (int q = 0; q < 5; ++q) {
        float4 v = hp[q];
        hv[q*4+0] = fmaxf(v.x, 0.f);
        hv[q*4+1] = fmaxf(v.y, 0.f);
        hv[q*4+2] = fmaxf(v.z, 0.f);
        hv[q*4+3] = fmaxf(v.w, 0.f);
    }
    float o0 = sb2[0], o1 = sb2[1];
    #pragma unroll
    for (int h = 0; h < 20; ++h) { o0 += hv[h]*sr[h*2]; o1 += hv[h]*sr[h*2+1]; }
    out2[(size_t)n*2 + 0] = o0;
    out2[(size_t)n*2 + 1] = o1;
    #pragma unroll
    for (int l = 0; l < 4; ++l) {
        float p0 = 0.f, p1 = 0.f;
        #pragma unroll
        for (int h = 0; h < 20; ++h) {
            p0 += hv[h]*st[l*40 + h*2];
            p1 += hv[h]*st[l*40 + h*2 + 1];
        }
        P2[(size_t)n*8 + l*2 + 0] = p0;
        P2[(size_t)n*8 + l*2 + 1] = p1;
    }
}

__global__ __launch_bounds__(256) void edge_scatter2(
    const int* __restrict__ ei, const float4* __restrict__ wedge2,
    const float4* __restrict__ P2, float* __restrict__ out2, int E)
{
    int e = blockIdx.x * 256 + threadIdx.x;
    if (e >= E) return;
    int s = ei[e], d = ei[E + e];
    float4 w = wedge2[e];
    float4 pa = P2[(size_t)s*2], pb = P2[(size_t)s*2 + 1];
    float y0 = w.x*pa.x + w.y*pa.z + w.z*pb.x + w.w*pb.z;
    float y1 = w.x*pa.y + w.y*pa.w + w.z*pb.y + w.w*pb.w;
    atomicAdd(out2 + (size_t)d*2 + 0, y0);
    atomicAdd(out2 + (size_t)d*2 + 1, y1);
    float4 qa = P2[(size_t)d*2], qb = P2[(size_t)d*2 + 1];
    float z0 = w.x*qa.x + w.y*qa.z + w.z*qb.x + w.w*qb.z;
    float z1 = w.x*qa.y + w.y*qa.w + w.z*qb.y + w.w*qb.w;
    atomicAdd(out2 + (size_t)s*2 + 0, z0);
    atomicAdd(out2 + (size_t)s*2 + 1, z1);
}

__global__ __launch_bounds__(256) void logsoftmax_k(
    const float* __restrict__ out2, float* __restrict__ out, int N)
{
    int n = blockIdx.x * 256 + threadIdx.x;
    if (n >= N) return;
    float o0 = out2[(size_t)n*2], o1 = out2[(size_t)n*2 + 1];
    float m = fmaxf(o0, o1);
    float lse = m + logf(expf(o0 - m) + expf(o1 - m));
    out[(size_t)n*2]     = o0 - lse;
    out[(size_t)n*2 + 1] = o1 - lse;
}

extern "C" void kernel_launch(void* const* d_in, const int* in_sizes, int n_in,
                              void* d_out, int out_size, void* d_ws, size_t ws_size,
                              hipStream_t stream)
{
    const float* x     = (const float*)d_in[0];
    const int*   ei    = (const int*)d_in[1];
    const float* attr  = (const float*)d_in[2];
    const float* cut   = (const float*)d_in[3];
    const float* cw1   = (const float*)d_in[4];
    const float* cb1   = (const float*)d_in[5];
    const float* f1w1  = (const float*)d_in[6];
    const float* f1b1  = (const float*)d_in[7];
    const float* f2w1  = (const float*)d_in[8];
    const float* f2b1  = (const float*)d_in[9];
    const float* th1   = (const float*)d_in[10];
    const float* rt1   = (const float*)d_in[11];
    const float* bs1   = (const float*)d_in[12];
    const float* cw2   = (const float*)d_in[13];
    const float* cb2   = (const float*)d_in[14];
    const float* f1w2  = (const float*)d_in[15];
    const float* f1b2  = (const float*)d_in[16];
    const float* f2w2  = (const float*)d_in[17];
    const float* f2b2  = (const float*)d_in[18];
    const float* th2   = (const float*)d_in[19];
    const float* rt2   = (const float*)d_in[20];
    const float* bs2   = (const float*)d_in[21];

    const int N = in_sizes[0] / 64;
    const int E = in_sizes[1] / 2;
    const int M = 2 * E;
    const int NB = (N + 127) >> SHIFT;
    const size_t NBB = (size_t)NB * BCAP;

    // ---- tier-A workspace layout (words); total ~121.8 MB (<=123.3 proven) ----
    size_t W = 0;
    float* ws = (float*)d_ws;
    uint2* wedge1h = (uint2*)(ws + W);     W += (size_t)E * 2;
    uint2* wedge2h = (uint2*)(ws + W);     W += (size_t)E * 2;
    uint2* tmp     = (uint2*)(ws + W);     W += NBB * 2;   // entries -> pw2 (alias)
    unsigned* fin  = (unsigned*)(ws + W);  W += NBB;
    uint2* pw1     = (uint2*)(ws + W);     W += NBB * 2;
    int* off       = (int*)(ws + W);       W += N;
    int* deg       = (int*)(ws + W);       W += N;
    int* bcur      = (int*)(ws + W);       W += NB;
    W = (W + 31) & ~(size_t)31;
    __half* x_h = (__half*)(ws + W);                  // 32N words
    float*  h1  = ws + W + (size_t)N * 32;            // 20N
    __half* P2h = (__half*)(ws + W + (size_t)N * 52); // 4N words
    float*  o2  = ws + W + (size_t)N * 56;            // 2N
    size_t need_new = W + (size_t)N * 58;

    bool okNew = (NB <= NB_MAX) && (E <= (1 << 21)) && (N <= (1 << 17)) &&
                 (ws_size / 4 >= need_new);

    if (okNew) {
        const int FB = (E + 255) / 256;
        const int PB = (N * 8 + 255) / 256;
        filter_prep_kernel<<<FB + PB, 256, 0, stream>>>(
            attr, cut, cw1, cb1, f1w1, f1b1, f2w1, f2b1,
            cw2, cb2, f1w2, f1b2, f2w2, f2b2,
            wedge1h, wedge2h, nullptr, nullptr, bcur, NB, E,
            x, rt1, bs1, h1, x_h, N, FB);
        passB_kernel<<<(M + CHUNKB - 1) / CHUNKB, 256, 0, stream>>>(
            ei, bcur, tmp, E, M, NB);
        passC_kernel<<<NB, 256, 0, stream>>>(
            tmp, bcur, wedge1h, wedge2h, fin, pw1, off, deg, N);
        gather1_fused<<<(N * 8 + 255) / 256, 256, 0, stream>>>(
            off, deg, fin, pw1, x_h, h1,
            th1, rt2, th2, bs2, o2, P2h, N);
        gather2_lsm_kernel<<<(N * 8 + 255) / 256, 256, 0, stream>>>(
            off, deg, fin, tmp /*pw2*/, P2h, o2, (float*)d_out, N);
    } else {
        // Fallback: atomic scatter (correct but slow). Independent layout.
        float* fw1 = ws;                           // 4E
        float* fw2 = fw1 + (size_t)E * 4;          // 4E
        float* P1  = fw2 + (size_t)E * 4;          // 80N (dummy wedge targets)
        float* fh1 = P1  + (size_t)N * 80;         // 20N
        float* fP2 = fh1 + (size_t)N * 20;         // 8N
        float* fo2 = fP2 + (size_t)N * 8;          // 2N
        int*   fbc = (int*)(fo2 + (size_t)N * 2);  // NB (dummy bcur)
        const int FB = (E + 255) / 256;
        filter_prep_kernel<<<FB, 256, 0, stream>>>(
            attr, cut, cw1, cb1, f1w1, f1b1, f2w1, f2b1,
            cw2, cb2, f1w2, f1b2, f2w2, f2b2,
            (uint2*)P1, (uint2*)P1, (float4*)fw1, (float4*)fw2, fbc,
            NB <= NB_MAX ? NB : NB_MAX, E,
            x, rt1, bs1, fh1, (__half*)fP2, N, FB);
        node_prep1<<<(N + 7) / 8, 256, 0, stream>>>(x, rt1, th1, bs1, fh1, P1, N);
        edge_scatter1<<<(E + 255) / 256, 256, 0, stream>>>(
            ei, (const float4*)fw1, (const float4*)P1, fh1, E);
        node_prep2<<<(N + 255) / 256, 256, 0, stream>>>(fh1, rt2, th2, bs2, fo2, fP2, N);
        edge_scatter2<<<(E + 255) / 256, 256, 0, stream>>>(
            ei, (const float4*)fw2, (const float4*)fP2, fo2, E);
        logsoftmax_k<<<(N + 255) / 256, 256, 0, stream>>>(fo2, (float*)d_out, N);
    }
}

// Round 14
// 593.969 us; speedup vs baseline: 1.5360x; 1.1762x over previous
//
#include <hip/hip_runtime.h>
#include <hip/hip_fp16.h>
#include <math.h>

// Problem constants: F_IN=64, K=16, C=20, L=4, H1=20, H2=2
// N=100k nodes, E=1.6M undirected edges, M=2E=3.2M directed entries.
//
// R10-R13 post-mortems: physically permuting per-edge payloads into node
// order costs >=200us of fabric traffic (line-granular overfetch) — more than
// it saves in the gathers. Revert to the R9 structure (best measured, 602us):
// gathers pay random reads directly; entries' chunk-order keeps wedge streams
// quasi-sorted (L2-friendly) for free. Only change vs R9: wedges stored fp16
// (halves both gathers' wedge stream bytes; packing/unpacking proven R11/R13).

#define SHIFT   7
#define NB_MAX  1024
#define CHUNKB  6144
#define BCAP    4608

// ---------------- K1: filter net (both layers, fp16) + prep (block split) -------
// fp16 mode (w1f==null): both layers packed fp16 -> wedge1h/wedge2h.
// Fallback mode: fp32 float4 both layers -> w1f/w2f.
__global__ __launch_bounds__(256) void filter_prep_kernel(
    const float* __restrict__ attr, const float* __restrict__ cutoffs,
    const float* __restrict__ cw1, const float* __restrict__ cb1,
    const float* __restrict__ f1w1, const float* __restrict__ f1b1,
    const float* __restrict__ f2w1, const float* __restrict__ f2b1,
    const float* __restrict__ cw2, const float* __restrict__ cb2,
    const float* __restrict__ f1w2, const float* __restrict__ f1b2,
    const float* __restrict__ f2w2, const float* __restrict__ f2b2,
    uint2* __restrict__ wedge1h, uint2* __restrict__ wedge2h,
    float4* __restrict__ w1f, float4* __restrict__ w2f,
    int* __restrict__ bcur, int NB, int E,
    const float* __restrict__ x, const float* __restrict__ root1,
    const float* __restrict__ bias1, float* __restrict__ h1,
    __half* __restrict__ x_h, int N, int FB)
{
    int tid = threadIdx.x;
    if ((int)blockIdx.x >= FB) {
        __shared__ float r1s[64 * 21];
        __shared__ float sb[20];
        for (int i = tid; i < 1280; i += 256) {
            int f = i / 20, h = i % 20;
            r1s[f*21 + h] = root1[i];
        }
        if (tid < 20) sb[tid] = bias1[tid];
        __syncthreads();
        int t = ((int)blockIdx.x - FB) * 256 + tid;
        int n = t >> 3, q = t & 7;
        if (n >= N) return;
        const float4* xr = (const float4*)(x + (size_t)n*64 + q*8);
        float4 va = xr[0], vb = xr[1];
        float xf[8] = {va.x, va.y, va.z, va.w, vb.x, vb.y, vb.z, vb.w};
        __half hh[8];
        #pragma unroll
        for (int j = 0; j < 8; ++j) hh[j] = __float2half(xf[j]);
        *(uint4*)(x_h + (size_t)n*64 + q*8) = *(const uint4*)hh;
        float p[20];
        #pragma unroll
        for (int h = 0; h < 20; ++h) p[h] = 0.f;
        #pragma unroll
        for (int j = 0; j < 8; ++j) {
            float xv = xf[j];
            int base = (q*8 + j) * 21;
            #pragma unroll
            for (int h = 0; h < 20; ++h) p[h] += xv * r1s[base + h];
        }
        #pragma unroll
        for (int m = 1; m < 8; m <<= 1) {
            #pragma unroll
            for (int h = 0; h < 20; ++h) p[h] += __shfl_xor(p[h], m, 64);
        }
        if (q < 5) {
            float4 o;
            o.x = p[q*4+0] + sb[q*4+0];
            o.y = p[q*4+1] + sb[q*4+1];
            o.z = p[q*4+2] + sb[q*4+2];
            o.w = p[q*4+3] + sb[q*4+3];
            *(float4*)(h1 + (size_t)n*20 + q*4) = o;
        }
        return;
    }
    // ---------------- filter body ----------------
    __shared__ float s_cut[16];
    __shared__ float s_w[2][344];
    __shared__ float tab[2 * 20 * 64];
    int gb = blockIdx.x * 256 + tid;
    if (gb < NB) bcur[gb] = gb * BCAP;
    if (tid < 16) s_cut[tid] = cutoffs[tid];
    for (int i = tid; i < 344; i += 256) {
        float v1, v2;
        if (i < 120)      { v1 = cw1[i];       v2 = cw2[i]; }
        else if (i < 140) { v1 = cb1[i-120];   v2 = cb2[i-120]; }
        else if (i < 300) { v1 = f1w1[i-140];  v2 = f1w2[i-140]; }
        else if (i < 308) { v1 = f1b1[i-300];  v2 = f1b2[i-300]; }
        else if (i < 340) { v1 = f2w1[i-308];  v2 = f2w2[i-308]; }
        else              { v1 = f2b1[i-340];  v2 = f2b2[i-340]; }
        s_w[0][i] = v1; s_w[1][i] = v2;
    }
    __syncthreads();
    if (tid < 40) {
        int l = tid / 20, ch = tid % 20;
        const float* W = s_w[l];
        float w00 = W[ch*6+0], w01 = W[ch*6+1], w02 = W[ch*6+2];
        float w10 = W[ch*6+3], w11 = W[ch*6+4], w12 = W[ch*6+5];
        float b = W[120 + ch];
        float* tb = &tab[(l*20 + ch) * 64];
        tb[0]  = w01*s_cut[0]  + w02*s_cut[1];
        for (int k = 1; k <= 14; ++k)
            tb[k] = w00*s_cut[k-1] + w01*s_cut[k] + w02*s_cut[k+1];
        tb[15] = w00*s_cut[14] + w01*s_cut[15];
        float pm = tb[1]; tb[16+1] = pm;
        for (int j = 2; j <= 14; ++j) { pm = fminf(pm, tb[j]); tb[16+j] = pm; }
        float qm = tb[14]; tb[32+14] = qm;
        for (int j = 13; j >= 1; --j) { qm = fminf(qm, tb[j]); tb[32+j] = qm; }
        tb[48] = w00 + w01 + w02;
        tb[49] = w01 + w02;
        tb[50] = w00 + w01;
        tb[51] = w10 + w11 + w12;
        tb[52] = w10 + w11;
        tb[53] = w10;
        tb[54] = w11;
        tb[55] = w12;
        tb[56] = b;
        tb[57] = tb[0];
        tb[58] = tb[15];
        tb[59] = 0.f;
    }
    __syncthreads();
    int e = gb;
    if (e >= E) return;

    float a = attr[e];
    int idx = 0;
    #pragma unroll
    for (int k = 0; k < 16; ++k) idx += (a > s_cut[k]) ? 1 : 0;

    #pragma unroll
    for (int layer = 0; layer < 2; ++layer) {
        const float* W = s_w[layer];
        float h[20];
        #pragma unroll
        for (int c = 0; c < 20; ++c) {
            const float* tb = &tab[(layer*20 + c) * 64];
            const float4* tb4 = (const float4*)tb;
            float4 A  = tb4[12];
            float4 B  = tb4[13];
            float4 Cv = tb4[14];
            float b = Cv.x;
            float base = fmaf(A.x, a, b);
            float y0 = fmaf(A.y, a, b) - Cv.y;
            y0 += (idx >= 1 ? B.z : 0.f) + (idx >= 2 ? B.w : 0.f);
            float m = y0;
            float y15 = fmaf(A.z, a, b) - Cv.z;
            y15 += (idx >= 15 ? B.y : 0.f) + (idx >= 16 ? B.z : 0.f);
            m = fmaxf(m, y15);
            { int j = idx - 2; j = j > 14 ? 14 : j;
              float v = base + A.w - tb[16 + j];
              m = (idx >= 3) ? fmaxf(m, v) : m; }
            { float v = base + B.x - tb[(idx >= 2 && idx <= 15) ? (idx-1) : 1];
              m = (idx >= 2 && idx <= 15) ? fmaxf(m, v) : m; }
            { float v = base + B.y - tb[(idx >= 1 && idx <= 14) ? idx : 1];
              m = (idx >= 1 && idx <= 14) ? fmaxf(m, v) : m; }
            { int j = idx + 1; j = j < 1 ? 1 : j;
              float v = base - tb[32 + (j > 14 ? 14 : j)];
              m = (idx <= 13) ? fmaxf(m, v) : m; }
            h[c] = fmaxf(m, 0.f);
        }
        float g[8];
        {
            const float4* bj4 = (const float4*)&W[300];
            float4 bj0 = bj4[0], bj1 = bj4[1];
            float bj[8] = {bj0.x,bj0.y,bj0.z,bj0.w,bj1.x,bj1.y,bj1.z,bj1.w};
            #pragma unroll
            for (int j = 0; j < 8; ++j) {
                const float4* wj = (const float4*)&W[140 + j*20];
                float4 q0=wj[0], q1=wj[1], q2=wj[2], q3=wj[3], q4=wj[4];
                float t = bj[j];
                t += q0.x*h[0]  + q0.y*h[1]  + q0.z*h[2]  + q0.w*h[3];
                t += q1.x*h[4]  + q1.y*h[5]  + q1.z*h[6]  + q1.w*h[7];
                t += q2.x*h[8]  + q2.y*h[9]  + q2.z*h[10] + q2.w*h[11];
                t += q3.x*h[12] + q3.y*h[13] + q3.z*h[14] + q3.w*h[15];
                t += q4.x*h[16] + q4.y*h[17] + q4.z*h[18] + q4.w*h[19];
                g[j] = fmaxf(t, 0.f);
            }
        }
        float wv[4];
        {
            const float4* bl4 = (const float4*)&W[340];
            float4 bl = bl4[0];
            float blv[4] = {bl.x, bl.y, bl.z, bl.w};
            #pragma unroll
            for (int l = 0; l < 4; ++l) {
                const float4* wl = (const float4*)&W[308 + l*8];
                float4 r0 = wl[0], r1 = wl[1];
                float t = blv[l];
                t += r0.x*g[0] + r0.y*g[1] + r0.z*g[2] + r0.w*g[3];
                t += r1.x*g[4] + r1.y*g[5] + r1.z*g[6] + r1.w*g[7];
                wv[l] = fmaxf(t, 0.f);
            }
        }
        if (w1f != nullptr) {
            float4 wo = make_float4(wv[0], wv[1], wv[2], wv[3]);
            if (layer == 0) w1f[e] = wo; else w2f[e] = wo;
        } else {
            __half2 p01 = __floats2half2_rn(wv[0], wv[1]);
            __half2 p23 = __floats2half2_rn(wv[2], wv[3]);
            uint2 pk;
            pk.x = *(unsigned*)&p01;
            pk.y = *(unsigned*)&p23;
            if (layer == 0) wedge1h[e] = pk; else wedge2h[e] = pk;
        }
    }
}

// ---------------- K2: scatter directed entries into capacity buckets ------------
// uint2 entry: x = nbr node, y = we | own7<<22  (ei read sequentially)
__global__ __launch_bounds__(256) void passB_kernel(
    const int* __restrict__ ei, int* __restrict__ bcur, uint2* __restrict__ tmp,
    int E, int M, int NB)
{
    __shared__ int hist[NB_MAX];
    __shared__ int lbase[NB_MAX];
    __shared__ int gpos[NB_MAX];
    __shared__ int aux[256];
    __shared__ uint2 stage[CHUNKB];
    int tid = threadIdx.x;
    int start = blockIdx.x * CHUNKB;
    if (start >= M) return;
    int cnt = M - start; if (cnt > CHUNKB) cnt = CHUNKB;
    for (int i = tid; i < NB_MAX; i += 256) hist[i] = 0;
    __syncthreads();
    for (int i = tid; i < cnt; i += 256) {
        int de = start + i;
        int own = ei[de < E ? de + E : de - E];
        atomicAdd(&hist[own >> SHIFT], 1);
    }
    __syncthreads();
    {
        int t4 = tid * 4;
        int a0 = hist[t4], a1 = hist[t4+1], a2 = hist[t4+2], a3 = hist[t4+3];
        aux[tid] = a0 + a1 + a2 + a3;
        __syncthreads();
        for (int off = 1; off < 256; off <<= 1) {
            int v = (tid >= off) ? aux[tid - off] : 0;
            __syncthreads();
            aux[tid] += v;
            __syncthreads();
        }
        int te = (tid == 0) ? 0 : aux[tid - 1];
        lbase[t4]   = te;
        lbase[t4+1] = te + a0;
        lbase[t4+2] = te + a0 + a1;
        lbase[t4+3] = te + a0 + a1 + a2;
    }
    __syncthreads();
    for (int b = tid; b < NB; b += 256) {
        int cb = hist[b];
        gpos[b] = cb ? atomicAdd(&bcur[b], cb) : 0;
    }
    __syncthreads();
    for (int i = tid; i < NB_MAX; i += 256) hist[i] = 0;
    __syncthreads();
    for (int i = tid; i < cnt; i += 256) {
        int de = start + i;
        int j = de < E ? de : de - E;
        int own = ei[de < E ? de + E : de - E];
        unsigned nbr = (unsigned)ei[de];
        int b = own >> SHIFT;
        int p = atomicAdd(&hist[b], 1);
        stage[lbase[b] + p] = make_uint2(nbr, (unsigned)j | ((unsigned)(own & 127) << 22));
    }
    __syncthreads();
    int wave = tid >> 6, lane = tid & 63;
    for (int b = wave; b < NB; b += 4) {
        int n_b = hist[b];
        if (!n_b) continue;
        int lo = lbase[b], g = gpos[b];
        int lim = (b + 1) * BCAP;
        for (int k = lane; k < n_b; k += 64) {
            if (g + k < lim) tmp[(size_t)g + k] = stage[lo + k];
        }
    }
}

// ---------------- K3: per-bucket node sort in place -> (off, deg) ---------------
__global__ __launch_bounds__(256) void passC_kernel(
    uint2* __restrict__ tmp, const int* __restrict__ bcur,
    int* __restrict__ off, int* __restrict__ deg, int N)
{
    __shared__ uint2 ordered[BCAP];
    __shared__ int hist[128], nexcl[128], cur[128], s2[128];
    int tid = threadIdx.x;
    int b = blockIdx.x;
    int lo = b * BCAP;
    int cnt = bcur[b] - lo;
    if (cnt > BCAP) cnt = BCAP;
    if (tid < 128) hist[tid] = 0;
    __syncthreads();
    for (int i = tid; i < cnt; i += 256)
        atomicAdd(&hist[(tmp[(size_t)lo + i].y >> 22) & 127], 1);
    __syncthreads();
    if (tid < 128) s2[tid] = hist[tid];
    __syncthreads();
    for (int o = 1; o < 128; o <<= 1) {
        int v = (tid < 128 && tid >= o) ? s2[tid - o] : 0;
        __syncthreads();
        if (tid < 128) s2[tid] += v;
        __syncthreads();
    }
    if (tid < 128) {
        int excl = s2[tid] - hist[tid];
        nexcl[tid] = excl;
        cur[tid] = 0;
        int node = (b << SHIFT) + tid;
        if (node < N) { off[node] = lo + excl; deg[node] = hist[tid]; }
    }
    __syncthreads();
    for (int i = tid; i < cnt; i += 256) {
        uint2 en = tmp[(size_t)lo + i];
        int ol = (en.y >> 22) & 127;
        int p = atomicAdd(&cur[ol], 1);
        ordered[nexcl[ol] + p] = en;
    }
    __syncthreads();
    for (int i = tid; i < cnt; i += 256) tmp[(size_t)lo + i] = ordered[i];
}

// ---------------- K4: gather layer 1 (2-edge, fp16 wedge) + fused node_prep2 ----
__global__ __launch_bounds__(256) void gather1_fused(
    const int* __restrict__ off, const int* __restrict__ deg,
    const uint2* __restrict__ fin, const uint2* __restrict__ wedge1h,
    const __half* __restrict__ x_h, const float* __restrict__ h1,
    const float* __restrict__ theta1,
    const float* __restrict__ root2, const float* __restrict__ theta2,
    const float* __restrict__ bias2,
    float* __restrict__ o2, __half* __restrict__ P2h, int N)
{
    __shared__ float th[4 * 64 * 21];
    __shared__ float w2s[200];
    __shared__ float w2b[2];
    int tid = threadIdx.x;
    for (int i = tid; i < 5120; i += 256) {
        int l = i / 1280, f = (i / 20) % 64, h = i % 20;
        th[(l*64 + f)*21 + h] = theta1[i];
    }
    for (int i = tid; i < 200; i += 256) {
        int o = i / 20, h = i % 20;
        float v;
        if (o < 2) v = root2[h*2 + o];
        else { int l = (o-2) >> 1, jj = (o-2) & 1; v = theta2[l*40 + h*2 + jj]; }
        w2s[i] = v;
    }
    if (tid < 2) w2b[tid] = bias2[tid];
    __syncthreads();
    int t = blockIdx.x * 256 + tid;
    int n = t >> 3, q = t & 7;
    if (n >= N) return;
    int s = off[n];
    int c = deg[n];
    const uint2* sl = fin + s;
    float acc[4][8];
    #pragma unroll
    for (int l = 0; l < 4; ++l)
        #pragma unroll
        for (int j = 0; j < 8; ++j) acc[l][j] = 0.f;
    int half = (c + 1) >> 1;
    for (int i = 0; i < half; ++i) {
        uint2 e1 = sl[i];
        int has2 = (i + half) < c;
        uint2 e2 = has2 ? sl[i + half] : e1;
        int nbr1 = (int)e1.x, nbr2 = (int)e2.x;
        unsigned we1 = e1.y & 0x3FFFFFu, we2 = e2.y & 0x3FFFFFu;
        uint2 k1 = wedge1h[we1];
        uint2 k2 = wedge1h[we2];
        __half2 a01 = *(__half2*)&k1.x, a23 = *(__half2*)&k1.y;
        __half2 b01 = *(__half2*)&k2.x, b23 = *(__half2*)&k2.y;
        float2 f0 = __half22float2(a01), f1 = __half22float2(a23);
        float2 g0 = __half22float2(b01), g1 = __half22float2(b23);
        float z = has2 ? 1.f : 0.f;
        g0.x *= z; g0.y *= z; g1.x *= z; g1.y *= z;
        uint4 hx1 = *(const uint4*)(x_h + (size_t)nbr1*64 + q*8);
        uint4 hx2 = *(const uint4*)(x_h + (size_t)nbr2*64 + q*8);
        const __half* hp1 = (const __half*)&hx1;
        const __half* hp2 = (const __half*)&hx2;
        #pragma unroll
        for (int j2 = 0; j2 < 8; ++j2) {
            float xa = __half2float(hp1[j2]);
            float xb = __half2float(hp2[j2]);
            acc[0][j2] += f0.x * xa + g0.x * xb;
            acc[1][j2] += f0.y * xa + g0.y * xb;
            acc[2][j2] += f1.x * xa + g1.x * xb;
            acc[3][j2] += f1.y * xa + g1.y * xb;
        }
    }
    float p[20];
    #pragma unroll
    for (int h = 0; h < 20; ++h) p[h] = 0.f;
    #pragma unroll
    for (int l = 0; l < 4; ++l) {
        #pragma unroll
        for (int j2 = 0; j2 < 8; ++j2) {
            float a = acc[l][j2];
            int base = ((l << 6) + (q << 3) + j2) * 21;
            #pragma unroll
            for (int h = 0; h < 20; ++h) p[h] += a * th[base + h];
        }
    }
    #pragma unroll
    for (int m = 1; m < 8; m <<= 1) {
        #pragma unroll
        for (int h = 0; h < 20; ++h) p[h] += __shfl_xor(p[h], m, 64);
    }
    const float4* hb = (const float4*)(h1 + (size_t)n*20);
    float hv[20];
    #pragma unroll
    for (int qq = 0; qq < 5; ++qq) {
        float4 v = hb[qq];
        hv[qq*4+0] = fmaxf(p[qq*4+0] + v.x, 0.f);
        hv[qq*4+1] = fmaxf(p[qq*4+1] + v.y, 0.f);
        hv[qq*4+2] = fmaxf(p[qq*4+2] + v.z, 0.f);
        hv[qq*4+3] = fmaxf(p[qq*4+3] + v.w, 0.f);
    }
    for (int o = q; o < 10; o += 8) {
        float v = (o < 2) ? w2b[o] : 0.f;
        #pragma unroll
        for (int h = 0; h < 20; ++h) v += hv[h] * w2s[o*20 + h];
        if (o < 2) o2[(size_t)n*2 + o] = v;
        else       P2h[(size_t)n*8 + (o - 2)] = __float2half(v);
    }
}

// ---------------- K5: gather layer 2 (fp16 wedge + fp16 P2) + log_softmax -------
__global__ __launch_bounds__(256) void gather2_lsm_kernel(
    const int* __restrict__ off, const int* __restrict__ deg,
    const uint2* __restrict__ fin, const uint2* __restrict__ wedge2h,
    const __half* __restrict__ P2h, const float* __restrict__ o2,
    float* __restrict__ out, int N)
{
    int t = blockIdx.x * 256 + threadIdx.x;
    int n = t >> 3, r = t & 7;
    if (n >= N) return;
    int s = off[n];
    int c = deg[n];
    const uint2* sl = fin + s;
    float o0 = 0.f, o1 = 0.f;
    for (int i = r; i < c; i += 8) {
        uint2 en = sl[i];
        int nbr = (int)en.x;
        unsigned we = en.y & 0x3FFFFFu;
        uint2 k = wedge2h[we];
        __half2 a01 = *(__half2*)&k.x, a23 = *(__half2*)&k.y;
        float2 w01 = __half22float2(a01), w23 = __half22float2(a23);
        uint4 hx = *(const uint4*)(P2h + (size_t)nbr * 8);
        const __half* ph = (const __half*)&hx;
        o0 += w01.x*__half2float(ph[0]) + w01.y*__half2float(ph[2])
            + w23.x*__half2float(ph[4]) + w23.y*__half2float(ph[6]);
        o1 += w01.x*__half2float(ph[1]) + w01.y*__half2float(ph[3])
            + w23.x*__half2float(ph[5]) + w23.y*__half2float(ph[7]);
    }
    #pragma unroll
    for (int m = 1; m < 8; m <<= 1) {
        o0 += __shfl_xor(o0, m, 64);
        o1 += __shfl_xor(o1, m, 64);
    }
    if (r == 0) {
        o0 += o2[(size_t)n*2];
        o1 += o2[(size_t)n*2 + 1];
        float mx = fmaxf(o0, o1);
        float lse = mx + logf(expf(o0 - mx) + expf(o1 - mx));
        out[(size_t)n*2]     = o0 - lse;
        out[(size_t)n*2 + 1] = o1 - lse;
    }
}

// ================= Fallback path (atomic scatter, R1-style) =====================
__global__ __launch_bounds__(256) void node_prep1(
    const float* __restrict__ x, const float* __restrict__ root1,
    const float* __restrict__ theta1, const float* __restrict__ bias1,
    float* __restrict__ h1, float* __restrict__ P1, int N)
{
    __shared__ float Ws[64 * 100];
    __shared__ float xs[8 * 64];
    __shared__ float sb[20];
    int tid = threadIdx.x;
    for (int i = tid; i < 6400; i += 256) {
        int f = i / 100, c = i % 100;
        float v;
        if (c < 20) v = root1[f*20 + c];
        else { int l = (c-20)/20, hh = (c-20)%20; v = theta1[l*1280 + f*20 + hh]; }
        Ws[i] = v;
    }
    if (tid < 20) sb[tid] = bias1[tid];
    int nb = blockIdx.x * 8;
    for (int i = tid; i < 512; i += 256) {
        int nl = i >> 6, f = i & 63;
        int n = nb + nl;
        xs[i] = (n < N) ? x[(size_t)n*64 + f] : 0.f;
    }
    __syncthreads();
    for (int i = tid; i < 800; i += 256) {
        int nl = i / 100, c = i % 100;
        int n = nb + nl;
        if (n >= N) continue;
        float acc = 0.f;
        #pragma unroll 16
        for (int f = 0; f < 64; ++f) acc += xs[nl*64 + f] * Ws[f*100 + c];
        if (c < 20) h1[(size_t)n*20 + c] = acc + sb[c];
        else        P1[(size_t)n*80 + (c - 20)] = acc;
    }
}

__global__ __launch_bounds__(256) void edge_scatter1(
    const int* __restrict__ ei, const float4* __restrict__ wedge1,
    const float4* __restrict__ P1, float* __restrict__ h1, int E)
{
    int e = blockIdx.x * 256 + threadIdx.x;
    if (e >= E) return;
    int s = ei[e], d = ei[E + e];
    float4 w = wedge1[e];
    const float4* Ps = P1 + (size_t)s * 20;
    const float4* Pd = P1 + (size_t)d * 20;
    float* Hs = h1 + (size_t)s * 20;
    float* Hd = h1 + (size_t)d * 20;
    #pragma unroll
    for (int q = 0; q < 5; ++q) {
        float4 a0 = Ps[q], a1 = Ps[5+q], a2 = Ps[10+q], a3 = Ps[15+q];
        atomicAdd(Hd + q*4 + 0, w.x*a0.x + w.y*a1.x + w.z*a2.x + w.w*a3.x);
        atomicAdd(Hd + q*4 + 1, w.x*a0.y + w.y*a1.y + w.z*a2.y + w.w*a3.y);
        atomicAdd(Hd + q*4 + 2, w.x*a0.z + w.y*a1.z + w.z*a2.z + w.w*a3.z);
        atomicAdd(Hd + q*4 + 3, w.x*a0.w + w.y*a1.w + w.z*a2.w + w.w*a3.w);
        float4 b0 = Pd[q], b1 = Pd[5+q], b2 = Pd[10+q], b3 = Pd[15+q];
        atomicAdd(Hs + q*4 + 0, w.x*b0.x + w.y*b1.x + w.z*b2.x + w.w*b3.x);
        atomicAdd(Hs + q*4 + 1, w.x*b0.y + w.y*b1.y + w.z*b2.y + w.w*b3.y);
        atomicAdd(Hs + q*4 + 2, w.x*b0.z + w.y*b1.z + w.z*b2.z + w.w*b3.z);
        atomicAdd(Hs + q*4 + 3, w.x*b0.w + w.y*b1.w + w.z*b2.w + w.w*b3.w);
    }
}

__global__ __launch_bounds__(256) void node_prep2(
    const float* __restrict__ h1, const float* __restrict__ root2,
    const float* __restrict__ theta2, const float* __restrict__ bias2,
    float* __restrict__ out2, float* __restrict__ P2, int N)
{
    __shared__ float sr[40], st[160], sb2[2];
    int tid = threadIdx.x;
    if (tid < 40) sr[tid] = root2[tid];
    if (tid >= 64 && tid < 224) st[tid - 64] = theta2[tid - 64];
    if (tid < 2) sb2[tid] = bias2[tid];
    __syncthreads();
    int n = blockIdx.x * 256 + tid;
    if (n >= N) return;
    float hv[20];
    const float4* hp = (const float4*)(h1 + (size_t)n * 20);
    #pragma unroll
    for (int q = 0; q < 5; ++q) {
        float4 v = hp[q];
        hv[q*4+0] = fmaxf(v.x, 0.f);
        hv[q*4+1] = fmaxf(v.y, 0.f);
        hv[q*4+2] = fmaxf(v.z, 0.f);
        hv[q*4+3] = fmaxf(v.w, 0.f);
    }
    float o0 = sb2[0], o1 = sb2[1];
    #pragma unroll
    for (int h = 0; h < 20; ++h) { o0 += hv[h]*sr[h*2]; o1 += hv[h]*sr[h*2+1]; }
    out2[(size_t)n*2 + 0] = o0;
    out2[(size_t)n*2 + 1] = o1;
    #pragma unroll
    for (int l = 0; l < 4; ++l) {
        float p0 = 0.f, p1 = 0.f;
        #pragma unroll
        for (int h = 0; h < 20; ++h) {
            p0 += hv[h]*st[l*40 + h*2];
            p1 += hv[h]*st[l*40 + h*2 + 1];
        }
        P2[(size_t)n*8 + l*2 + 0] = p0;
        P2[(size_t)n*8 + l*2 + 1] = p1;
    }
}

__global__ __launch_bounds__(256) void edge_scatter2(
    const int* __restrict__ ei, const float4* __restrict__ wedge2,
    const float4* __restrict__ P2, float* __restrict__ out2, int E)
{
    int e = blockIdx.x * 256 + threadIdx.x;
    if (e >= E) return;
    int s = ei[e], d = ei[E + e];
    float4 w = wedge2[e];
    float4 pa = P2[(size_t)s*2], pb = P2[(size_t)s*2 + 1];
    float y0 = w.x*pa.x + w.y*pa.z + w.z*pb.x + w.w*pb.z;
    float y1 = w.x*pa.y + w.y*pa.w + w.z*pb.y + w.w*pb.w;
    atomicAdd(out2 + (size_t)d*2 + 0, y0);
    atomicAdd(out2 + (size_t)d*2 + 1, y1);
    float4 qa = P2[(size_t)d*2], qb = P2[(size_t)d*2 + 1];
    float z0 = w.x*qa.x + w.y*qa.z + w.z*qb.x + w.w*qb.z;
    float z1 = w.x*qa.y + w.y*qa.w + w.z*qb.y + w.w*qb.w;
    atomicAdd(out2 + (size_t)s*2 + 0, z0);
    atomicAdd(out2 + (size_t)s*2 + 1, z1);
}

__global__ __launch_bounds__(256) void logsoftmax_k(
    const float* __restrict__ out2, float* __restrict__ out, int N)
{
    int n = blockIdx.x * 256 + threadIdx.x;
    if (n >= N) return;
    float o0 = out2[(size_t)n*2], o1 = out2[(size_t)n*2 + 1];
    float m = fmaxf(o0, o1);
    float lse = m + logf(expf(o0 - m) + expf(o1 - m));
    out[(size_t)n*2]     = o0 - lse;
    out[(size_t)n*2 + 1] = o1 - lse;
}

extern "C" void kernel_launch(void* const* d_in, const int* in_sizes, int n_in,
                              void* d_out, int out_size, void* d_ws, size_t ws_size,
                              hipStream_t stream)
{
    const float* x     = (const float*)d_in[0];
    const int*   ei    = (const int*)d_in[1];
    const float* attr  = (const float*)d_in[2];
    const float* cut   = (const float*)d_in[3];
    const float* cw1   = (const float*)d_in[4];
    const float* cb1   = (const float*)d_in[5];
    const float* f1w1  = (const float*)d_in[6];
    const float* f1b1  = (const float*)d_in[7];
    const float* f2w1  = (const float*)d_in[8];
    const float* f2b1  = (const float*)d_in[9];
    const float* th1   = (const float*)d_in[10];
    const float* rt1   = (const float*)d_in[11];
    const float* bs1   = (const float*)d_in[12];
    const float* cw2   = (const float*)d_in[13];
    const float* cb2   = (const float*)d_in[14];
    const float* f1w2  = (const float*)d_in[15];
    const float* f1b2  = (const float*)d_in[16];
    const float* f2w2  = (const float*)d_in[17];
    const float* f2b2  = (const float*)d_in[18];
    const float* th2   = (const float*)d_in[19];
    const float* rt2   = (const float*)d_in[20];
    const float* bs2   = (const float*)d_in[21];

    const int N = in_sizes[0] / 64;
    const int E = in_sizes[1] / 2;
    const int M = 2 * E;
    const int NB = (N + 127) >> SHIFT;
    const size_t NBB = (size_t)NB * BCAP;

    // ---- tier-A workspace layout (words); total ~79 MB ----
    size_t W = 0;
    float* ws = (float*)d_ws;
    uint2* wedge1h = (uint2*)(ws + W);     W += (size_t)E * 2;
    uint2* wedge2h = (uint2*)(ws + W);     W += (size_t)E * 2;
    uint2* tmp     = (uint2*)(ws + W);     W += NBB * 2;
    int* off       = (int*)(ws + W);       W += N;
    int* deg       = (int*)(ws + W);       W += N;
    int* bcur      = (int*)(ws + W);       W += NB;
    W = (W + 31) & ~(size_t)31;
    __half* x_h = (__half*)(ws + W);                  // 32N words
    float*  h1  = ws + W + (size_t)N * 32;            // 20N
    __half* P2h = (__half*)(ws + W + (size_t)N * 52); // 4N words
    float*  o2  = ws + W + (size_t)N * 56;            // 2N
    size_t need_new = W + (size_t)N * 58;

    bool okNew = (NB <= NB_MAX) && (E <= (1 << 21)) && (N <= (1 << 17)) &&
                 (ws_size / 4 >= need_new);

    if (okNew) {
        const int FB = (E + 255) / 256;
        const int PB = (N * 8 + 255) / 256;
        filter_prep_kernel<<<FB + PB, 256, 0, stream>>>(
            attr, cut, cw1, cb1, f1w1, f1b1, f2w1, f2b1,
            cw2, cb2, f1w2, f1b2, f2w2, f2b2,
            wedge1h, wedge2h, nullptr, nullptr, bcur, NB, E,
            x, rt1, bs1, h1, x_h, N, FB);
        passB_kernel<<<(M + CHUNKB - 1) / CHUNKB, 256, 0, stream>>>(
            ei, bcur, tmp, E, M, NB);
        passC_kernel<<<NB, 256, 0, stream>>>(tmp, bcur, off, deg, N);
        gather1_fused<<<(N * 8 + 255) / 256, 256, 0, stream>>>(
            off, deg, tmp, wedge1h, x_h, h1,
            th1, rt2, th2, bs2, o2, P2h, N);
        gather2_lsm_kernel<<<(N * 8 + 255) / 256, 256, 0, stream>>>(
            off, deg, tmp, wedge2h, P2h, o2, (float*)d_out, N);
    } else {
        // Fallback: atomic scatter (correct but slow). Independent layout.
        float* fw1 = ws;                           // 4E
        float* fw2 = fw1 + (size_t)E * 4;          // 4E
        float* P1  = fw2 + (size_t)E * 4;          // 80N (dummy wedge targets)
        float* fh1 = P1  + (size_t)N * 80;         // 20N
        float* fP2 = fh1 + (size_t)N * 20;         // 8N
        float* fo2 = fP2 + (size_t)N * 8;          // 2N
        int*   fbc = (int*)(fo2 + (size_t)N * 2);  // NB (dummy bcur)
        const int FB = (E + 255) / 256;
        filter_prep_kernel<<<FB, 256, 0, stream>>>(
            attr, cut, cw1, cb1, f1w1, f1b1, f2w1, f2b1,
            cw2, cb2, f1w2, f1b2, f2w2, f2b2,
            (uint2*)P1, (uint2*)P1, (float4*)fw1, (float4*)fw2, fbc,
            NB <= NB_MAX ? NB : NB_MAX, E,
            x, rt1, bs1, fh1, (__half*)fP2, N, FB);
        node_prep1<<<(N + 7) / 8, 256, 0, stream>>>(x, rt1, th1, bs1, fh1, P1, N);
        edge_scatter1<<<(E + 255) / 256, 256, 0, stream>>>(
            ei, (const float4*)fw1, (const float4*)P1, fh1, E);
        node_prep2<<<(N + 255) / 256, 256, 0, stream>>>(fh1, rt2, th2, bs2, fo2, fP2, N);
        edge_scatter2<<<(E + 255) / 256, 256, 0, stream>>>(
            ei, (const float4*)fw2, (const float4*)fP2, fo2, E);
        logsoftmax_k<<<(N + 255) / 256, 256, 0, stream>>>(fo2, (float*)d_out, N);
    }
}